// Round 17
// baseline (401.932 us; speedup 1.0000x reference)
//
#include <hip/hip_runtime.h>
#include <hip/hip_bf16.h>
#include <math.h>

#define BATCH 16
#define NNODE 1024
#define DIM   512
#define KNN   16
#define KP1   17
#define NCAND 18
#define NEG   0.2f
#define BT    128   // block tile
#define NCH   16    // n-chunks for column reductions

typedef __attribute__((ext_vector_type(8))) short bf16x8;
typedef __attribute__((ext_vector_type(4))) float f32x4;

// async global->LDS, 16B per lane; LDS dest = wave-uniform base + lane*16 (m104)
#define GLOAD16(g, l) __builtin_amdgcn_global_load_lds( \
    (const __attribute__((address_space(1))) unsigned int*)(g), \
    (__attribute__((address_space(3))) unsigned int*)(l), 16, 0, 0)

__device__ __forceinline__ unsigned short f2bf(float f) {
    unsigned u = __float_as_uint(f);
    unsigned r = (u + 0x7FFFu + ((u >> 16) & 1u)) >> 16;   // RNE
    return (unsigned short)r;
}
__device__ __forceinline__ float bf2f(unsigned short h) {
    return __uint_as_float(((unsigned)h) << 16);
}
__device__ __forceinline__ void split_store(float v, unsigned short* hi, unsigned short* lo, size_t idx) {
    unsigned short h = f2bf(v);
    hi[idx] = h;
    lo[idx] = f2bf(v - bf2f(h));
}

// ---------------- zero maxabs + encoded max-pool accumulator ----------------
__global__ void init_misc(unsigned* __restrict__ maxabs, unsigned* __restrict__ genc) {
    int gid = blockIdx.x * 256 + threadIdx.x;
    if (gid < BATCH) maxabs[gid] = 0u;
    if (gid < BATCH * DIM) genc[gid] = 0u;        // enc(-INF) > 0, so 0 is identity
}

// ---------------- column mean, stage 1: partial sums over 64-node chunks ----------------
__global__ __launch_bounds__(256) void colmean_part(const float* __restrict__ x, float* __restrict__ part) {
    int b = blockIdx.x, dc = blockIdx.y, ch = blockIdx.z;
    int d = dc * 256 + threadIdx.x;
    const float* p = x + ((size_t)b * NNODE + ch * (NNODE / NCH)) * DIM + d;
    float s = 0.f;
    #pragma unroll 4
    for (int n = 0; n < NNODE / NCH; ++n) s += p[(size_t)n * DIM];
    part[((size_t)b * NCH + ch) * DIM + d] = s;
}
__global__ void colmean_fin(const float* __restrict__ part, float* __restrict__ mean) {
    int id = blockIdx.x * 256 + threadIdx.x;   // b*DIM + d
    int b = id >> 9, d = id & (DIM - 1);
    float s = 0.f;
    #pragma unroll
    for (int ch = 0; ch < NCH; ++ch) s += part[((size_t)b * NCH + ch) * DIM + d];
    mean[id] = s * (1.0f / NNODE);
}

// ---------------- fused: row squared norms + x -> bf16 (one pass over x) ----------------
__global__ __launch_bounds__(256) void rowsq_xtobf(const float* __restrict__ x,
                                                   float* __restrict__ sq,
                                                   unsigned short* __restrict__ xh) {
    int row = blockIdx.x * 4 + (threadIdx.x >> 6);
    int l = threadIdx.x & 63;
    const float* p = x + (size_t)row * DIM + l * 8;
    float4 a = *(const float4*)p;
    float4 b = *(const float4*)(p + 4);
    float s = a.x * a.x + a.y * a.y + a.z * a.z + a.w * a.w
            + b.x * b.x + b.y * b.y + b.z * b.z + b.w * b.w;
    ushort4 ha, hb;
    ha.x = f2bf(a.x); ha.y = f2bf(a.y); ha.z = f2bf(a.z); ha.w = f2bf(a.w);
    hb.x = f2bf(b.x); hb.y = f2bf(b.y); hb.z = f2bf(b.z); hb.w = f2bf(b.w);
    unsigned short* q = xh + (size_t)row * DIM + l * 8;
    *(ushort4*)q = ha;
    *(ushort4*)(q + 4) = hb;
    #pragma unroll
    for (int off = 32; off > 0; off >>= 1) s += __shfl_down(s, off, 64);
    if (l == 0) sq[row] = s;
}

// ---------------- approx distances via bf16 MFMA -> u32 selection keys ----------------
__global__ __launch_bounds__(256, 2) void dist_mfma(const unsigned short* __restrict__ xh,
                                                    const float* __restrict__ sq,
                                                    unsigned* __restrict__ keys) {
    __shared__ unsigned short AhL[128][64], BhL[128][64];
    int fh = blockIdx.x;
    int xcd = fh & 7, ord = fh >> 3;          // ord 0..127
    int mt = xcd * 16 + (ord >> 3);           // 0..127
    int nb = ord & 7;
    int b = mt >> 3;
    int m0 = mt * BT;
    int n0 = nb * BT;
    int bn0 = b * NNODE + n0;
    int t = threadIdx.x;
    int lane = t & 63, w = t >> 6;
    int wm = (w >> 1) * 64, wn = (w & 1) * 64;
    int fr = lane & 15, fk = (lane >> 4) * 8;
    f32x4 acc[4][4];
    #pragma unroll
    for (int i = 0; i < 4; ++i)
        #pragma unroll
        for (int j = 0; j < 4; ++j) acc[i][j] = (f32x4){0.f, 0.f, 0.f, 0.f};

    for (int k0 = 0; k0 < DIM; k0 += 64) {
        if (k0) __syncthreads();
        #pragma unroll
        for (int p = 0; p < 4; ++p) {
            int u = t + p * 256;              // 1024 issues of 16B cover 128x64 bf16
            int row = u >> 3, slot = u & 7;
            int gseg = (slot ^ (row & 7)) * 8;
            GLOAD16(xh + (size_t)(m0 + row) * DIM + k0 + gseg, &AhL[0][0] + u * 8);
            GLOAD16(xh + (size_t)(bn0 + row) * DIM + k0 + gseg, &BhL[0][0] + u * 8);
        }
        __syncthreads();
        #pragma unroll
        for (int s = 0; s < 2; ++s) {
            bf16x8 ah[4], bh[4];
            int ks = s * 4 + (fk >> 3);
            #pragma unroll
            for (int i = 0; i < 4; ++i) {
                int ra = wm + i * 16 + fr;
                ah[i] = *(const bf16x8*)&AhL[ra][(ks ^ (ra & 7)) * 8];
                int rb = wn + i * 16 + fr;
                bh[i] = *(const bf16x8*)&BhL[rb][(ks ^ (rb & 7)) * 8];
            }
            #pragma unroll
            for (int i = 0; i < 4; ++i)
                #pragma unroll
                for (int j = 0; j < 4; ++j)
                    acc[i][j] = __builtin_amdgcn_mfma_f32_16x16x32_bf16(ah[i], bh[j], acc[i][j], 0, 0, 0);
        }
    }
    const float* sqb = sq + b * NNODE;
    int mloc0 = m0 - b * NNODE;
    #pragma unroll
    for (int i = 0; i < 4; ++i) {
        int mloc = mloc0 + wm + i * 16 + (lane >> 4) * 4;
        #pragma unroll
        for (int j = 0; j < 4; ++j) {
            int n = n0 + wn + j * 16 + fr;
            float sqn = sqb[n];
            #pragma unroll
            for (int r = 0; r < 4; ++r) {
                float val = sqb[mloc + r] + sqn - 2.f * acc[i][j][r];
                unsigned kv = (__float_as_uint(val) & 0xFFFFFC00u) | (unsigned)n;
                if (mloc + r == n) kv = 0xFFFFFFFFu;
                keys[((size_t)b * NNODE + mloc + r) * NNODE + n] = kv;
            }
        }
    }
}

// ---------------- top-18 smallest keys per row: threshold walk ----------------
__global__ __launch_bounds__(256) void knn_kernel(const unsigned* __restrict__ keys, int* __restrict__ cand) {
    int row = blockIdx.x * 4 + (threadIdx.x >> 6);   // b*N + n
    int l = threadIdx.x & 63;
    const unsigned* src = keys + (size_t)row * NNODE;
    unsigned key[16];
    #pragma unroll
    for (int j = 0; j < 16; ++j) key[j] = src[l + (j << 6)];
    int* dst = cand + row * NCAND;
    unsigned T = 0;
    for (int it = 0; it < NCAND; ++it) {
        unsigned lmin = 0xFFFFFFFFu;
        #pragma unroll
        for (int j = 0; j < 16; ++j) {
            unsigned k = (key[j] > T) ? key[j] : 0xFFFFFFFFu;
            lmin = min(lmin, k);
        }
        #pragma unroll
        for (int off = 1; off < 64; off <<= 1) {
            unsigned o = (unsigned)__shfl_xor((int)lmin, off, 64);
            lmin = min(lmin, o);
        }
        T = lmin;
        if (l == 0) dst[it] = (int)(lmin & 1023u);
    }
}

// ---------------- exact f32 re-rank: wave per row ----------------
__global__ __launch_bounds__(256) void rerank_kernel(const float* __restrict__ x,
                                                     const float* __restrict__ sq,
                                                     const int* __restrict__ cand,
                                                     int* __restrict__ nbr) {
    int bid = blockIdx.x;                 // 4096 blocks
    int b = bid & (BATCH - 1);
    int w = threadIdx.x >> 6, l = threadIdx.x & 63;
    int m = (bid >> 4) * 4 + w;
    int row = b * NNODE + m;
    const float* xb = x + (size_t)b * NNODE * DIM;
    const float* sqb = sq + b * NNODE;
    const float* xm = xb + (size_t)m * DIM;
    float4 m0v = *(const float4*)(xm + l * 8);
    float4 m1v = *(const float4*)(xm + l * 8 + 4);
    float sqm = sqb[m];

    int idx[NCAND];
    #pragma unroll
    for (int c = 0; c < NCAND; ++c) idx[c] = cand[row * NCAND + c];

    float s[NCAND];
    #pragma unroll
    for (int half = 0; half < 2; ++half) {
        float4 j0[9], j1[9];
        #pragma unroll
        for (int i = 0; i < 9; ++i) {
            const float* xj = xb + (size_t)idx[half * 9 + i] * DIM;
            j0[i] = *(const float4*)(xj + l * 8);
            j1[i] = *(const float4*)(xj + l * 8 + 4);
        }
        #pragma unroll
        for (int i = 0; i < 9; ++i)
            s[half * 9 + i] = m0v.x * j0[i].x + m0v.y * j0[i].y + m0v.z * j0[i].z + m0v.w * j0[i].w
                            + m1v.x * j1[i].x + m1v.y * j1[i].y + m1v.z * j1[i].z + m1v.w * j1[i].w;
    }
    #pragma unroll
    for (int off = 32; off > 0; off >>= 1)
        #pragma unroll
        for (int c = 0; c < NCAND; ++c) s[c] += __shfl_xor(s[c], off, 64);

    unsigned long long key[NCAND];
    #pragma unroll
    for (int c = 0; c < NCAND; ++c) {
        float dv = sqm + sqb[idx[c]] - 2.f * s[c];
        key[c] = ((unsigned long long)__float_as_uint(dv) << 32) | (unsigned)idx[c];
    }
    unsigned long long mykey = ~0ull;
    int myidx = 0;
    #pragma unroll
    for (int c = 0; c < NCAND; ++c) {
        if (l == c) { mykey = key[c]; myidx = idx[c]; }
    }
    int rank = 0;
    #pragma unroll
    for (int c = 0; c < NCAND; ++c) rank += (key[c] < mykey) ? 1 : 0;

    int* dst = nbr + row * KP1;
    if (l < NCAND && rank < KNN) dst[rank] = myidx;
    if (l == 0) dst[KNN] = m;
}

// ---------------- per-graph max|x - mean| ----------------
__global__ __launch_bounds__(256) void maxabs_kernel(const float* __restrict__ x,
                                                     const float* __restrict__ mean,
                                                     unsigned* __restrict__ maxabs) {
    int b = blockIdx.y;
    const float* p = x + ((size_t)b * NNODE + blockIdx.x * 64) * DIM;
    const float* mb = mean + b * DIM;
    float m = 0.f;
    for (int i = threadIdx.x; i < 64 * DIM; i += 256) {
        int d = i & (DIM - 1);
        m = fmaxf(m, fabsf(p[i] - mb[d]));
    }
    __shared__ float red[256];
    red[threadIdx.x] = m; __syncthreads();
    for (int s = 128; s > 0; s >>= 1) {
        if (threadIdx.x < s) red[threadIdx.x] = fmaxf(red[threadIdx.x], red[threadIdx.x + s]);
        __syncthreads();
    }
    if (threadIdx.x == 0) atomicMax(maxabs + b, __float_as_uint(red[0]));
}

// ---------------- h0 = (x - mean) * 0.999999/maxabs -> split bf16 hi/lo ----------------
__global__ void normalize_kernel(const float* __restrict__ x, const float* __restrict__ mean,
                                 const unsigned* __restrict__ maxabs,
                                 unsigned short* __restrict__ h_hi, unsigned short* __restrict__ h_lo) {
    int id = blockIdx.x * 256 + threadIdx.x;
    int b = id >> 19;
    int d = id & (DIM - 1);
    float scale = 0.999999f / __uint_as_float(maxabs[b]);
    float v = (x[id] - mean[b * DIM + d]) * scale;
    split_store(v, h_hi, h_lo, id);
}

// ---------------- W[512x512] -> Wt hi/lo bf16 [n][k], all 3 layers in one launch ----------------
__global__ void wsplit_kernel(const float* __restrict__ W1, const float* __restrict__ W2,
                              const float* __restrict__ W3,
                              unsigned short* __restrict__ Wh1, unsigned short* __restrict__ Wl1,
                              unsigned short* __restrict__ Wh2, unsigned short* __restrict__ Wl2,
                              unsigned short* __restrict__ Wh3, unsigned short* __restrict__ Wl3) {
    int z = blockIdx.z;
    const float* W = (z == 0) ? W1 : (z == 1) ? W2 : W3;
    unsigned short* Wh = (z == 0) ? Wh1 : (z == 1) ? Wh2 : Wh3;
    unsigned short* Wl = (z == 0) ? Wl1 : (z == 1) ? Wl2 : Wl3;
    __shared__ float tile[32][33];
    int bx = blockIdx.x * 32, by = blockIdx.y * 32;
    int tx = threadIdx.x & 31, ty = threadIdx.x >> 5;
    #pragma unroll
    for (int i = 0; i < 4; ++i)
        tile[ty + i * 8][tx] = W[(size_t)(by + ty + i * 8) * DIM + bx + tx];
    __syncthreads();
    #pragma unroll
    for (int i = 0; i < 4; ++i) {
        int n = bx + ty + i * 8;
        float v = tile[tx][ty + i * 8];
        split_store(v, Wh, Wl, (size_t)n * DIM + by + tx);
    }
}

// ---------------- C f32 = (Ah+Al) . (Wh+Wl) + fused attvec partials ----------------
__global__ __launch_bounds__(256, 2) void gemm_mfma(const unsigned short* __restrict__ Agh,
                                                    const unsigned short* __restrict__ Agl,
                                                    const unsigned short* __restrict__ Bgh,
                                                    const unsigned short* __restrict__ Bgl,
                                                    const float* __restrict__ asrc,
                                                    const float* __restrict__ adst,
                                                    float* __restrict__ C,
                                                    float* __restrict__ pas,
                                                    float* __restrict__ pad) {
    __shared__ unsigned short AhL[128][64], AlL[128][64], BhL[128][64], BlL[128][64];
    __shared__ float asl[128], adl[128];
    int fh = blockIdx.x;
    int xcd = fh & 7, ord = fh >> 3;          // ord 0..63
    int mt = xcd * 16 + (ord >> 2);           // 0..127
    int nb = ord & 3;
    int m0 = mt * BT, n0 = nb * BT;
    int t = threadIdx.x;
    int lane = t & 63, w = t >> 6;
    int wm = (w >> 1) * 64, wn = (w & 1) * 64;
    int fr = lane & 15, fk = (lane >> 4) * 8;
    f32x4 acc[4][4];
    #pragma unroll
    for (int i = 0; i < 4; ++i)
        #pragma unroll
        for (int j = 0; j < 4; ++j) acc[i][j] = (f32x4){0.f, 0.f, 0.f, 0.f};

    for (int k0 = 0; k0 < DIM; k0 += 64) {
        if (k0) __syncthreads();
        #pragma unroll
        for (int p = 0; p < 4; ++p) {
            int u = t + p * 256;
            int row = u >> 3, slot = u & 7;
            int gseg = (slot ^ (row & 7)) * 8;
            size_t ga = (size_t)(m0 + row) * DIM + k0 + gseg;
            size_t gb = (size_t)(n0 + row) * DIM + k0 + gseg;
            GLOAD16(Agh + ga, &AhL[0][0] + u * 8);
            GLOAD16(Agl + ga, &AlL[0][0] + u * 8);
            GLOAD16(Bgh + gb, &BhL[0][0] + u * 8);
            GLOAD16(Bgl + gb, &BlL[0][0] + u * 8);
        }
        __syncthreads();
        #pragma unroll
        for (int s = 0; s < 2; ++s) {
            bf16x8 ah[4], al[4], bh[4], bl[4];
            int ks = s * 4 + (fk >> 3);
            #pragma unroll
            for (int i = 0; i < 4; ++i) {
                int ra = wm + i * 16 + fr;
                int sa = (ks ^ (ra & 7)) * 8;
                ah[i] = *(const bf16x8*)&AhL[ra][sa];
                al[i] = *(const bf16x8*)&AlL[ra][sa];
                int rb = wn + i * 16 + fr;
                int sb = (ks ^ (rb & 7)) * 8;
                bh[i] = *(const bf16x8*)&BhL[rb][sb];
                bl[i] = *(const bf16x8*)&BlL[rb][sb];
            }
            #pragma unroll
            for (int i = 0; i < 4; ++i)
                #pragma unroll
                for (int j = 0; j < 4; ++j)
                    acc[i][j] = __builtin_amdgcn_mfma_f32_16x16x32_bf16(ah[i], bh[j], acc[i][j], 0, 0, 0);
            #pragma unroll
            for (int i = 0; i < 4; ++i)
                #pragma unroll
                for (int j = 0; j < 4; ++j)
                    acc[i][j] = __builtin_amdgcn_mfma_f32_16x16x32_bf16(ah[i], bl[j], acc[i][j], 0, 0, 0);
            #pragma unroll
            for (int i = 0; i < 4; ++i)
                #pragma unroll
                for (int j = 0; j < 4; ++j)
                    acc[i][j] = __builtin_amdgcn_mfma_f32_16x16x32_bf16(al[i], bh[j], acc[i][j], 0, 0, 0);
        }
    }
    #pragma unroll
    for (int i = 0; i < 4; ++i) {
        int mrow = m0 + wm + i * 16 + (lane >> 4) * 4;
        #pragma unroll
        for (int j = 0; j < 4; ++j) {
            int col = n0 + wn + j * 16 + fr;
            #pragma unroll
            for (int r = 0; r < 4; ++r)
                C[(size_t)(mrow + r) * DIM + col] = acc[i][j][r];
        }
    }
    // ---- fused attvec partials over this block's 128-col slice ----
    float av[4], dv[4];
    #pragma unroll
    for (int j = 0; j < 4; ++j) {
        int col = n0 + wn + j * 16 + fr;
        av[j] = asrc[col];
        dv[j] = adst[col];
    }
    if (t < 128) { asl[t] = 0.f; adl[t] = 0.f; }
    __syncthreads();
    #pragma unroll
    for (int ph = 0; ph < 2; ++ph) {      // ph 0: wn==0 warps write; ph 1: wn==64 warps add
        if ((wn == 0) == (ph == 0)) {
            #pragma unroll
            for (int i = 0; i < 4; ++i)
                #pragma unroll
                for (int r = 0; r < 4; ++r) {
                    float sa = acc[i][0][r] * av[0] + acc[i][1][r] * av[1]
                             + acc[i][2][r] * av[2] + acc[i][3][r] * av[3];
                    float sd = acc[i][0][r] * dv[0] + acc[i][1][r] * dv[1]
                             + acc[i][2][r] * dv[2] + acc[i][3][r] * dv[3];
                    #pragma unroll
                    for (int off = 1; off < 16; off <<= 1) {
                        sa += __shfl_xor(sa, off, 64);
                        sd += __shfl_xor(sd, off, 64);
                    }
                    if (fr == 0) {
                        int rloc = wm + i * 16 + (lane >> 4) * 4 + r;
                        if (ph == 0) { asl[rloc] = sa;  adl[rloc] = sd; }
                        else         { asl[rloc] += sa; adl[rloc] += sd; }
                    }
                }
        }
        __syncthreads();
    }
    if (t < 128) {
        pas[(size_t)(m0 + t) * 4 + nb] = asl[t];
        pad[(size_t)(m0 + t) * 4 + nb] = adl[t];
    }
}

// ---------------- finish attvec: sum 4 n-block partials (fixed order) ----------------
__global__ void attvec_fin(const float* __restrict__ pas, const float* __restrict__ pad,
                           float* __restrict__ as_, float* __restrict__ ad_) {
    int id = blockIdx.x * 256 + threadIdx.x;    // row over B*N
    float4 a = *(const float4*)(pas + (size_t)id * 4);
    float4 d = *(const float4*)(pad + (size_t)id * 4);
    as_[id] = ((a.x + a.y) + a.z) + a.w;
    ad_[id] = ((d.x + d.y) + d.z) + d.w;
}

// ---------------- GAT attention + aggregation: wave-per-node ----------------
// Inline-asm gathers: all 34 dwordx4 loads pinned in flight (compiler kept sinking
// source-level loads, VGPR 36 / 14 TB/s L2 -> MLP-bound). Two waitcnt phases.
template<int RELU, int SPLIT>
__global__ __launch_bounds__(256) void aggr_kernel(const float* __restrict__ hp, const int* __restrict__ nbr,
                                                   const float* __restrict__ as_, const float* __restrict__ ad_,
                                                   const float* __restrict__ bias,
                                                   float* __restrict__ outf,
                                                   unsigned short* __restrict__ oh,
                                                   unsigned short* __restrict__ ol) {
    __shared__ float attL[4][KP1];
    __shared__ int   jjL[4][KP1];
    int bid = blockIdx.x;                 // B*N/4 blocks
    int b = bid & (BATCH - 1);
    int w = threadIdx.x >> 6, l = threadIdx.x & 63;
    int n = (bid >> 4) * 4 + w;
    int id = b * NNODE + n;

    float e = -INFINITY;
    if (l < KP1) {
        int j = nbr[id * KP1 + l];
        jjL[w][l] = j;
        e = as_[b * NNODE + j] + ad_[id];
        e = (e >= 0.f) ? e : NEG * e;
    }
    float mx = e;
    #pragma unroll
    for (int off = 16; off > 0; off >>= 1) mx = fmaxf(mx, __shfl_xor(mx, off, 64));
    float ex = (l < KP1) ? expf(e - mx) : 0.f;
    float sm = ex;
    #pragma unroll
    for (int off = 16; off > 0; off >>= 1) sm += __shfl_xor(sm, off, 64);
    if (l < KP1) attL[w][l] = ex / sm;

    const float* base = hp + (size_t)b * NNODE * DIM;
    int d0 = l * 8;
    float areg[KP1];
    const float* vp[KP1];
    #pragma unroll
    for (int k = 0; k < KP1; ++k) {
        areg[k] = attL[w][k];
        vp[k] = base + (size_t)jjL[w][k] * DIM + d0;
    }
    // consume bias BEFORE asm loads so compiler waitcnts don't drain our queue
    f32x4 o0 = *(const f32x4*)(bias + d0);
    f32x4 o1 = *(const f32x4*)(bias + d0 + 4);

    f32x4 v0[KP1], v1[KP1];
    #pragma unroll
    for (int k = 0; k < KP1; ++k)
        asm volatile("global_load_dwordx4 %0, %1, off" : "=&v"(v0[k]) : "v"(vp[k]));
    #pragma unroll
    for (int k = 0; k < KP1; ++k)
        asm volatile("global_load_dwordx4 %0, %1, off offset:16" : "=&v"(v1[k]) : "v"(vp[k]));
    asm volatile("s_waitcnt vmcnt(17)" ::: "memory");   // oldest 17 (= all v0) done
    __builtin_amdgcn_sched_barrier(0);
    #pragma unroll
    for (int k = 0; k < KP1; ++k) {
        float a = areg[k];
        o0[0] += a * v0[k][0]; o0[1] += a * v0[k][1];
        o0[2] += a * v0[k][2]; o0[3] += a * v0[k][3];
    }
    asm volatile("s_waitcnt vmcnt(0)" ::: "memory");
    __builtin_amdgcn_sched_barrier(0);
    #pragma unroll
    for (int k = 0; k < KP1; ++k) {
        float a = areg[k];
        o1[0] += a * v1[k][0]; o1[1] += a * v1[k][1];
        o1[2] += a * v1[k][2]; o1[3] += a * v1[k][3];
    }
    if (RELU) {
        #pragma unroll
        for (int i = 0; i < 4; ++i) {
            o0[i] = fmaxf(o0[i], 0.f);
            o1[i] = fmaxf(o1[i], 0.f);
        }
    }
    size_t idx = (size_t)id * DIM + d0;
    if (SPLIT) {
        float v[8] = {o0[0], o0[1], o0[2], o0[3], o1[0], o1[1], o1[2], o1[3]};
        unsigned hi[4], lo[4];
        #pragma unroll
        for (int i = 0; i < 4; ++i) {
            unsigned short h0 = f2bf(v[2 * i]),     h1 = f2bf(v[2 * i + 1]);
            unsigned short l0 = f2bf(v[2 * i] - bf2f(h0));
            unsigned short l1 = f2bf(v[2 * i + 1] - bf2f(h1));
            hi[i] = (unsigned)h0 | ((unsigned)h1 << 16);
            lo[i] = (unsigned)l0 | ((unsigned)l1 << 16);
        }
        *(uint4*)(oh + idx) = *(uint4*)hi;
        *(uint4*)(ol + idx) = *(uint4*)lo;
    } else {
        *(f32x4*)(outf + idx) = o0;
        *(f32x4*)(outf + idx + 4) = o1;
    }
}

// ---------------- global max pool: single kernel, monotonic-encoded atomicMax ----------------
__global__ __launch_bounds__(256) void maxpool_atomic(const float* __restrict__ h, unsigned* __restrict__ genc) {
    int b = blockIdx.x, dc = blockIdx.y, ch = blockIdx.z;
    int d = dc * 256 + threadIdx.x;
    const float* p = h + ((size_t)b * NNODE + ch * (NNODE / NCH)) * DIM + d;
    float m = -INFINITY;
    #pragma unroll 4
    for (int n = 0; n < NNODE / NCH; ++n) m = fmaxf(m, p[(size_t)n * DIM]);
    unsigned u = __float_as_uint(m);
    unsigned enc = (u & 0x80000000u) ? ~u : (u | 0x80000000u);   // order-preserving f32->u32
    atomicMax(genc + b * DIM + d, enc);
}

// ---------------- final linear g @ Wc + bc (decodes genc) ----------------
__global__ void final_kernel(const unsigned* __restrict__ genc, const float* __restrict__ Wc,
                             const float* __restrict__ bc, float* __restrict__ out) {
    int b = blockIdx.x, t = threadIdx.x;
    float s0 = 0.f, s1 = 0.f;
    for (int d = t; d < DIM; d += 256) {
        unsigned e = genc[b * DIM + d];
        unsigned u = (e & 0x80000000u) ? (e ^ 0x80000000u) : ~e;
        float v = __uint_as_float(u);
        s0 += v * Wc[d * 2 + 0];
        s1 += v * Wc[d * 2 + 1];
    }
    __shared__ float r0[256], r1[256];
    r0[t] = s0; r1[t] = s1; __syncthreads();
    for (int s = 128; s > 0; s >>= 1) {
        if (t < s) { r0[t] += r0[t + s]; r1[t] += r1[t + s]; }
        __syncthreads();
    }
    if (t == 0) { out[b * 2] = r0[0] + bc[0]; out[b * 2 + 1] = r1[0] + bc[1]; }
}

extern "C" void kernel_launch(void* const* d_in, const int* in_sizes, int n_in,
                              void* d_out, int out_size, void* d_ws, size_t ws_size,
                              hipStream_t stream) {
    const float* x     = (const float*)d_in[0];
    const float* W1    = (const float*)d_in[1];
    const float* asrc1 = (const float*)d_in[2];
    const float* adst1 = (const float*)d_in[3];
    const float* b1    = (const float*)d_in[4];
    const float* W2    = (const float*)d_in[5];
    const float* asrc2 = (const float*)d_in[6];
    const float* adst2 = (const float*)d_in[7];
    const float* b2    = (const float*)d_in[8];
    const float* W3    = (const float*)d_in[9];
    const float* asrc3 = (const float*)d_in[10];
    const float* adst3 = (const float*)d_in[11];
    const float* b3    = (const float*)d_in[12];
    const float* Wc    = (const float*)d_in[13];
    const float* bc    = (const float*)d_in[14];
    float* out = (float*)d_out;

    char* ws = (char*)d_ws;
    unsigned*       keys  = (unsigned*)ws;                         // 64MB (graph build only)
    float*          hp    = (float*)ws;                            // 32MB f32
    unsigned short* hA_hi = (unsigned short*)(ws + (32ull << 20)); // 16MB
    unsigned short* hA_lo = (unsigned short*)(ws + (48ull << 20)); // 16MB
    unsigned short* xh    = (unsigned short*)(ws + (64ull << 20)); // 16MB (graph build only)
    unsigned short* hB_hi = (unsigned short*)(ws + (64ull << 20)); // 16MB
    unsigned short* hB_lo = (unsigned short*)(ws + (80ull << 20)); // 16MB
    float*          h3    = (float*)(ws + (64ull << 20));          // 32MB, alias hB
    size_t off = 96ull << 20;
    unsigned short* Wt1h = (unsigned short*)(ws + off); off += (size_t)DIM * DIM * 2;
    unsigned short* Wt1l = (unsigned short*)(ws + off); off += (size_t)DIM * DIM * 2;
    unsigned short* Wt2h = (unsigned short*)(ws + off); off += (size_t)DIM * DIM * 2;
    unsigned short* Wt2l = (unsigned short*)(ws + off); off += (size_t)DIM * DIM * 2;
    unsigned short* Wt3h = (unsigned short*)(ws + off); off += (size_t)DIM * DIM * 2;
    unsigned short* Wt3l = (unsigned short*)(ws + off); off += (size_t)DIM * DIM * 2;
    int*      nbr    = (int*)(ws + off);      off += (size_t)BATCH * NNODE * KP1 * 4;
    int*      cand   = (int*)(ws + off);      off += (size_t)BATCH * NNODE * NCAND * 4;
    float*    sq     = (float*)(ws + off);    off += (size_t)BATCH * NNODE * 4;
    float*    mean   = (float*)(ws + off);    off += (size_t)BATCH * DIM * 4;
    unsigned* maxabs = (unsigned*)(ws + off); off += 256;
    float*    as_    = (float*)(ws + off);    off += (size_t)BATCH * NNODE * 4;
    float*    ad_    = (float*)(ws + off);    off += (size_t)BATCH * NNODE * 4;
    unsigned* genc   = (unsigned*)(ws + off); off += (size_t)BATCH * DIM * 4;
    float*    part   = (float*)(ws + off);    off += (size_t)BATCH * NCH * DIM * 4;  // 512KB scratch
    float*    pas    = part;                                   // 256KB (reuse, colmean done)
    float*    pad    = part + (size_t)BATCH * NNODE * 4;       // 256KB
    (void)ws_size; (void)in_sizes; (void)n_in; (void)out_size;

    const dim3 cgrid(BATCH, DIM / 256, NCH);
    // ---- graph construction: approx bf16 MFMA keys + exact f32 re-rank ----
    init_misc<<<32, 256, 0, stream>>>(maxabs, genc);
    colmean_part<<<cgrid, 256, 0, stream>>>(x, part);
    colmean_fin<<<BATCH * DIM / 256, 256, 0, stream>>>(part, mean);
    rowsq_xtobf<<<BATCH * NNODE / 4, 256, 0, stream>>>(x, sq, xh);
    dist_mfma<<<(NNODE / BT) * (BATCH * NNODE / BT), 256, 0, stream>>>(xh, sq, keys);
    knn_kernel<<<BATCH * NNODE / 4, 256, 0, stream>>>(keys, cand);
    rerank_kernel<<<BATCH * NNODE / 4, 256, 0, stream>>>(x, sq, cand, nbr);
    // ---- weights transpose + split (one launch) ----
    wsplit_kernel<<<dim3(16, 16, 3), 256, 0, stream>>>(W1, W2, W3, Wt1h, Wt1l, Wt2h, Wt2l, Wt3h, Wt3l);
    // ---- normalize -> hA (split bf16); keys/xh dead from here ----
    maxabs_kernel<<<dim3(16, BATCH), 256, 0, stream>>>(x, mean, maxabs);
    normalize_kernel<<<BATCH * NNODE * DIM / 256, 256, 0, stream>>>(x, mean, maxabs, hA_hi, hA_lo);

    const int ggrid = (DIM / BT) * (BATCH * NNODE / BT);   // 512 blocks (flat, XCD-swizzled)
    // layer 1
    gemm_mfma<<<ggrid, 256, 0, stream>>>(hA_hi, hA_lo, Wt1h, Wt1l, asrc1, adst1, hp, pas, pad);
    attvec_fin<<<BATCH * NNODE / 256, 256, 0, stream>>>(pas, pad, as_, ad_);
    aggr_kernel<1, 1><<<BATCH * NNODE / 4, 256, 0, stream>>>(hp, nbr, as_, ad_, b1, nullptr, hB_hi, hB_lo);
    // layer 2
    gemm_mfma<<<ggrid, 256, 0, stream>>>(hB_hi, hB_lo, Wt2h, Wt2l, asrc2, adst2, hp, pas, pad);
    attvec_fin<<<BATCH * NNODE / 256, 256, 0, stream>>>(pas, pad, as_, ad_);
    aggr_kernel<1, 1><<<BATCH * NNODE / 4, 256, 0, stream>>>(hp, nbr, as_, ad_, b2, nullptr, hA_hi, hA_lo);
    // layer 3
    gemm_mfma<<<ggrid, 256, 0, stream>>>(hA_hi, hA_lo, Wt3h, Wt3l, asrc3, adst3, hp, pas, pad);
    attvec_fin<<<BATCH * NNODE / 256, 256, 0, stream>>>(pas, pad, as_, ad_);
    aggr_kernel<0, 0><<<BATCH * NNODE / 4, 256, 0, stream>>>(hp, nbr, as_, ad_, b3, h3, nullptr, nullptr);
    // pool + classify
    maxpool_atomic<<<cgrid, 256, 0, stream>>>(h3, genc);
    final_kernel<<<BATCH, 256, 0, stream>>>(genc, Wc, bc, out);
}

// Round 18
// 367.290 us; speedup vs baseline: 1.0943x; 1.0943x over previous
//
#include <hip/hip_runtime.h>
#include <hip/hip_bf16.h>
#include <math.h>

#define BATCH 16
#define NNODE 1024
#define DIM   512
#define KNN   16
#define KP1   17
#define NCAND 18
#define NEG   0.2f
#define BT    128   // block tile
#define NCH   16    // n-chunks for column reductions

typedef __attribute__((ext_vector_type(8))) short bf16x8;
typedef __attribute__((ext_vector_type(4))) float f32x4;

// async global->LDS, 16B per lane; LDS dest = wave-uniform base + lane*16 (m104)
#define GLOAD16(g, l) __builtin_amdgcn_global_load_lds( \
    (const __attribute__((address_space(1))) unsigned int*)(g), \
    (__attribute__((address_space(3))) unsigned int*)(l), 16, 0, 0)

__device__ __forceinline__ unsigned short f2bf(float f) {
    unsigned u = __float_as_uint(f);
    unsigned r = (u + 0x7FFFu + ((u >> 16) & 1u)) >> 16;   // RNE
    return (unsigned short)r;
}
__device__ __forceinline__ float bf2f(unsigned short h) {
    return __uint_as_float(((unsigned)h) << 16);
}
__device__ __forceinline__ void split_store(float v, unsigned short* hi, unsigned short* lo, size_t idx) {
    unsigned short h = f2bf(v);
    hi[idx] = h;
    lo[idx] = f2bf(v - bf2f(h));
}

// ---------------- zero maxabs + encoded max-pool accumulator ----------------
__global__ void init_misc(unsigned* __restrict__ maxabs, unsigned* __restrict__ genc) {
    int gid = blockIdx.x * 256 + threadIdx.x;
    if (gid < BATCH) maxabs[gid] = 0u;
    if (gid < BATCH * DIM) genc[gid] = 0u;        // enc(-INF) > 0, so 0 is identity
}

// ---------------- column mean, stage 1: partial sums over 64-node chunks ----------------
__global__ __launch_bounds__(256) void colmean_part(const float* __restrict__ x, float* __restrict__ part) {
    int b = blockIdx.x, dc = blockIdx.y, ch = blockIdx.z;
    int d = dc * 256 + threadIdx.x;
    const float* p = x + ((size_t)b * NNODE + ch * (NNODE / NCH)) * DIM + d;
    float s = 0.f;
    #pragma unroll 4
    for (int n = 0; n < NNODE / NCH; ++n) s += p[(size_t)n * DIM];
    part[((size_t)b * NCH + ch) * DIM + d] = s;
}
__global__ void colmean_fin(const float* __restrict__ part, float* __restrict__ mean) {
    int id = blockIdx.x * 256 + threadIdx.x;   // b*DIM + d
    int b = id >> 9, d = id & (DIM - 1);
    float s = 0.f;
    #pragma unroll
    for (int ch = 0; ch < NCH; ++ch) s += part[((size_t)b * NCH + ch) * DIM + d];
    mean[id] = s * (1.0f / NNODE);
}

// ---------------- fused: row squared norms + x -> bf16 (one pass over x) ----------------
__global__ __launch_bounds__(256) void rowsq_xtobf(const float* __restrict__ x,
                                                   float* __restrict__ sq,
                                                   unsigned short* __restrict__ xh) {
    int row = blockIdx.x * 4 + (threadIdx.x >> 6);
    int l = threadIdx.x & 63;
    const float* p = x + (size_t)row * DIM + l * 8;
    float4 a = *(const float4*)p;
    float4 b = *(const float4*)(p + 4);
    float s = a.x * a.x + a.y * a.y + a.z * a.z + a.w * a.w
            + b.x * b.x + b.y * b.y + b.z * b.z + b.w * b.w;
    ushort4 ha, hb;
    ha.x = f2bf(a.x); ha.y = f2bf(a.y); ha.z = f2bf(a.z); ha.w = f2bf(a.w);
    hb.x = f2bf(b.x); hb.y = f2bf(b.y); hb.z = f2bf(b.z); hb.w = f2bf(b.w);
    unsigned short* q = xh + (size_t)row * DIM + l * 8;
    *(ushort4*)q = ha;
    *(ushort4*)(q + 4) = hb;
    #pragma unroll
    for (int off = 32; off > 0; off >>= 1) s += __shfl_down(s, off, 64);
    if (l == 0) sq[row] = s;
}

// ---------------- approx distances via bf16 MFMA -> u32 selection keys ----------------
__global__ __launch_bounds__(256, 2) void dist_mfma(const unsigned short* __restrict__ xh,
                                                    const float* __restrict__ sq,
                                                    unsigned* __restrict__ keys) {
    __shared__ unsigned short AhL[128][64], BhL[128][64];
    int fh = blockIdx.x;
    int xcd = fh & 7, ord = fh >> 3;          // ord 0..127
    int mt = xcd * 16 + (ord >> 3);           // 0..127
    int nb = ord & 7;
    int b = mt >> 3;
    int m0 = mt * BT;
    int n0 = nb * BT;
    int bn0 = b * NNODE + n0;
    int t = threadIdx.x;
    int lane = t & 63, w = t >> 6;
    int wm = (w >> 1) * 64, wn = (w & 1) * 64;
    int fr = lane & 15, fk = (lane >> 4) * 8;
    f32x4 acc[4][4];
    #pragma unroll
    for (int i = 0; i < 4; ++i)
        #pragma unroll
        for (int j = 0; j < 4; ++j) acc[i][j] = (f32x4){0.f, 0.f, 0.f, 0.f};

    for (int k0 = 0; k0 < DIM; k0 += 64) {
        if (k0) __syncthreads();
        #pragma unroll
        for (int p = 0; p < 4; ++p) {
            int u = t + p * 256;              // 1024 issues of 16B cover 128x64 bf16
            int row = u >> 3, slot = u & 7;
            int gseg = (slot ^ (row & 7)) * 8;
            GLOAD16(xh + (size_t)(m0 + row) * DIM + k0 + gseg, &AhL[0][0] + u * 8);
            GLOAD16(xh + (size_t)(bn0 + row) * DIM + k0 + gseg, &BhL[0][0] + u * 8);
        }
        __syncthreads();
        #pragma unroll
        for (int s = 0; s < 2; ++s) {
            bf16x8 ah[4], bh[4];
            int ks = s * 4 + (fk >> 3);
            #pragma unroll
            for (int i = 0; i < 4; ++i) {
                int ra = wm + i * 16 + fr;
                ah[i] = *(const bf16x8*)&AhL[ra][(ks ^ (ra & 7)) * 8];
                int rb = wn + i * 16 + fr;
                bh[i] = *(const bf16x8*)&BhL[rb][(ks ^ (rb & 7)) * 8];
            }
            #pragma unroll
            for (int i = 0; i < 4; ++i)
                #pragma unroll
                for (int j = 0; j < 4; ++j)
                    acc[i][j] = __builtin_amdgcn_mfma_f32_16x16x32_bf16(ah[i], bh[j], acc[i][j], 0, 0, 0);
        }
    }
    const float* sqb = sq + b * NNODE;
    int mloc0 = m0 - b * NNODE;
    #pragma unroll
    for (int i = 0; i < 4; ++i) {
        int mloc = mloc0 + wm + i * 16 + (lane >> 4) * 4;
        #pragma unroll
        for (int j = 0; j < 4; ++j) {
            int n = n0 + wn + j * 16 + fr;
            float sqn = sqb[n];
            #pragma unroll
            for (int r = 0; r < 4; ++r) {
                float val = sqb[mloc + r] + sqn - 2.f * acc[i][j][r];
                unsigned kv = (__float_as_uint(val) & 0xFFFFFC00u) | (unsigned)n;
                if (mloc + r == n) kv = 0xFFFFFFFFu;
                keys[((size_t)b * NNODE + mloc + r) * NNODE + n] = kv;
            }
        }
    }
}

// ---------------- top-18 smallest keys per row: threshold walk ----------------
__global__ __launch_bounds__(256) void knn_kernel(const unsigned* __restrict__ keys, int* __restrict__ cand) {
    int row = blockIdx.x * 4 + (threadIdx.x >> 6);   // b*N + n
    int l = threadIdx.x & 63;
    const unsigned* src = keys + (size_t)row * NNODE;
    unsigned key[16];
    #pragma unroll
    for (int j = 0; j < 16; ++j) key[j] = src[l + (j << 6)];
    int* dst = cand + row * NCAND;
    unsigned T = 0;
    for (int it = 0; it < NCAND; ++it) {
        unsigned lmin = 0xFFFFFFFFu;
        #pragma unroll
        for (int j = 0; j < 16; ++j) {
            unsigned k = (key[j] > T) ? key[j] : 0xFFFFFFFFu;
            lmin = min(lmin, k);
        }
        #pragma unroll
        for (int off = 1; off < 64; off <<= 1) {
            unsigned o = (unsigned)__shfl_xor((int)lmin, off, 64);
            lmin = min(lmin, o);
        }
        T = lmin;
        if (l == 0) dst[it] = (int)(lmin & 1023u);
    }
}

// ---------------- exact f32 re-rank: wave per row ----------------
__global__ __launch_bounds__(256) void rerank_kernel(const float* __restrict__ x,
                                                     const float* __restrict__ sq,
                                                     const int* __restrict__ cand,
                                                     int* __restrict__ nbr) {
    int bid = blockIdx.x;                 // 4096 blocks
    int b = bid & (BATCH - 1);
    int w = threadIdx.x >> 6, l = threadIdx.x & 63;
    int m = (bid >> 4) * 4 + w;
    int row = b * NNODE + m;
    const float* xb = x + (size_t)b * NNODE * DIM;
    const float* sqb = sq + b * NNODE;
    const float* xm = xb + (size_t)m * DIM;
    float4 m0v = *(const float4*)(xm + l * 8);
    float4 m1v = *(const float4*)(xm + l * 8 + 4);
    float sqm = sqb[m];

    int idx[NCAND];
    #pragma unroll
    for (int c = 0; c < NCAND; ++c) idx[c] = cand[row * NCAND + c];

    float s[NCAND];
    #pragma unroll
    for (int half = 0; half < 2; ++half) {
        float4 j0[9], j1[9];
        #pragma unroll
        for (int i = 0; i < 9; ++i) {
            const float* xj = xb + (size_t)idx[half * 9 + i] * DIM;
            j0[i] = *(const float4*)(xj + l * 8);
            j1[i] = *(const float4*)(xj + l * 8 + 4);
        }
        #pragma unroll
        for (int i = 0; i < 9; ++i)
            s[half * 9 + i] = m0v.x * j0[i].x + m0v.y * j0[i].y + m0v.z * j0[i].z + m0v.w * j0[i].w
                            + m1v.x * j1[i].x + m1v.y * j1[i].y + m1v.z * j1[i].z + m1v.w * j1[i].w;
    }
    #pragma unroll
    for (int off = 32; off > 0; off >>= 1)
        #pragma unroll
        for (int c = 0; c < NCAND; ++c) s[c] += __shfl_xor(s[c], off, 64);

    unsigned long long key[NCAND];
    #pragma unroll
    for (int c = 0; c < NCAND; ++c) {
        float dv = sqm + sqb[idx[c]] - 2.f * s[c];
        key[c] = ((unsigned long long)__float_as_uint(dv) << 32) | (unsigned)idx[c];
    }
    unsigned long long mykey = ~0ull;
    int myidx = 0;
    #pragma unroll
    for (int c = 0; c < NCAND; ++c) {
        if (l == c) { mykey = key[c]; myidx = idx[c]; }
    }
    int rank = 0;
    #pragma unroll
    for (int c = 0; c < NCAND; ++c) rank += (key[c] < mykey) ? 1 : 0;

    int* dst = nbr + row * KP1;
    if (l < NCAND && rank < KNN) dst[rank] = myidx;
    if (l == 0) dst[KNN] = m;
}

// ---------------- per-graph max|x - mean| ----------------
__global__ __launch_bounds__(256) void maxabs_kernel(const float* __restrict__ x,
                                                     const float* __restrict__ mean,
                                                     unsigned* __restrict__ maxabs) {
    int b = blockIdx.y;
    const float* p = x + ((size_t)b * NNODE + blockIdx.x * 64) * DIM;
    const float* mb = mean + b * DIM;
    float m = 0.f;
    for (int i = threadIdx.x; i < 64 * DIM; i += 256) {
        int d = i & (DIM - 1);
        m = fmaxf(m, fabsf(p[i] - mb[d]));
    }
    __shared__ float red[256];
    red[threadIdx.x] = m; __syncthreads();
    for (int s = 128; s > 0; s >>= 1) {
        if (threadIdx.x < s) red[threadIdx.x] = fmaxf(red[threadIdx.x], red[threadIdx.x + s]);
        __syncthreads();
    }
    if (threadIdx.x == 0) atomicMax(maxabs + b, __float_as_uint(red[0]));
}

// ---------------- h0 = (x - mean) * 0.999999/maxabs -> split bf16 hi/lo ----------------
__global__ void normalize_kernel(const float* __restrict__ x, const float* __restrict__ mean,
                                 const unsigned* __restrict__ maxabs,
                                 unsigned short* __restrict__ h_hi, unsigned short* __restrict__ h_lo) {
    int id = blockIdx.x * 256 + threadIdx.x;
    int b = id >> 19;
    int d = id & (DIM - 1);
    float scale = 0.999999f / __uint_as_float(maxabs[b]);
    float v = (x[id] - mean[b * DIM + d]) * scale;
    split_store(v, h_hi, h_lo, id);
}

// ---------------- W[512x512] -> Wt hi/lo bf16 [n][k], all 3 layers in one launch ----------------
__global__ void wsplit_kernel(const float* __restrict__ W1, const float* __restrict__ W2,
                              const float* __restrict__ W3,
                              unsigned short* __restrict__ Wh1, unsigned short* __restrict__ Wl1,
                              unsigned short* __restrict__ Wh2, unsigned short* __restrict__ Wl2,
                              unsigned short* __restrict__ Wh3, unsigned short* __restrict__ Wl3) {
    int z = blockIdx.z;
    const float* W = (z == 0) ? W1 : (z == 1) ? W2 : W3;
    unsigned short* Wh = (z == 0) ? Wh1 : (z == 1) ? Wh2 : Wh3;
    unsigned short* Wl = (z == 0) ? Wl1 : (z == 1) ? Wl2 : Wl3;
    __shared__ float tile[32][33];
    int bx = blockIdx.x * 32, by = blockIdx.y * 32;
    int tx = threadIdx.x & 31, ty = threadIdx.x >> 5;
    #pragma unroll
    for (int i = 0; i < 4; ++i)
        tile[ty + i * 8][tx] = W[(size_t)(by + ty + i * 8) * DIM + bx + tx];
    __syncthreads();
    #pragma unroll
    for (int i = 0; i < 4; ++i) {
        int n = bx + ty + i * 8;
        float v = tile[tx][ty + i * 8];
        split_store(v, Wh, Wl, (size_t)n * DIM + by + tx);
    }
}

// ---------------- C f32 = (Ah+Al) . (Wh+Wl) + fused attvec partials ----------------
__global__ __launch_bounds__(256, 2) void gemm_mfma(const unsigned short* __restrict__ Agh,
                                                    const unsigned short* __restrict__ Agl,
                                                    const unsigned short* __restrict__ Bgh,
                                                    const unsigned short* __restrict__ Bgl,
                                                    const float* __restrict__ asrc,
                                                    const float* __restrict__ adst,
                                                    float* __restrict__ C,
                                                    float* __restrict__ pas,
                                                    float* __restrict__ pad) {
    __shared__ unsigned short AhL[128][64], AlL[128][64], BhL[128][64], BlL[128][64];
    __shared__ float asl[128], adl[128];
    int fh = blockIdx.x;
    int xcd = fh & 7, ord = fh >> 3;          // ord 0..63
    int mt = xcd * 16 + (ord >> 2);           // 0..127
    int nb = ord & 3;
    int m0 = mt * BT, n0 = nb * BT;
    int t = threadIdx.x;
    int lane = t & 63, w = t >> 6;
    int wm = (w >> 1) * 64, wn = (w & 1) * 64;
    int fr = lane & 15, fk = (lane >> 4) * 8;
    f32x4 acc[4][4];
    #pragma unroll
    for (int i = 0; i < 4; ++i)
        #pragma unroll
        for (int j = 0; j < 4; ++j) acc[i][j] = (f32x4){0.f, 0.f, 0.f, 0.f};

    for (int k0 = 0; k0 < DIM; k0 += 64) {
        if (k0) __syncthreads();
        #pragma unroll
        for (int p = 0; p < 4; ++p) {
            int u = t + p * 256;
            int row = u >> 3, slot = u & 7;
            int gseg = (slot ^ (row & 7)) * 8;
            size_t ga = (size_t)(m0 + row) * DIM + k0 + gseg;
            size_t gb = (size_t)(n0 + row) * DIM + k0 + gseg;
            GLOAD16(Agh + ga, &AhL[0][0] + u * 8);
            GLOAD16(Agl + ga, &AlL[0][0] + u * 8);
            GLOAD16(Bgh + gb, &BhL[0][0] + u * 8);
            GLOAD16(Bgl + gb, &BlL[0][0] + u * 8);
        }
        __syncthreads();
        #pragma unroll
        for (int s = 0; s < 2; ++s) {
            bf16x8 ah[4], al[4], bh[4], bl[4];
            int ks = s * 4 + (fk >> 3);
            #pragma unroll
            for (int i = 0; i < 4; ++i) {
                int ra = wm + i * 16 + fr;
                int sa = (ks ^ (ra & 7)) * 8;
                ah[i] = *(const bf16x8*)&AhL[ra][sa];
                al[i] = *(const bf16x8*)&AlL[ra][sa];
                int rb = wn + i * 16 + fr;
                int sb = (ks ^ (rb & 7)) * 8;
                bh[i] = *(const bf16x8*)&BhL[rb][sb];
                bl[i] = *(const bf16x8*)&BlL[rb][sb];
            }
            #pragma unroll
            for (int i = 0; i < 4; ++i)
                #pragma unroll
                for (int j = 0; j < 4; ++j)
                    acc[i][j] = __builtin_amdgcn_mfma_f32_16x16x32_bf16(ah[i], bh[j], acc[i][j], 0, 0, 0);
            #pragma unroll
            for (int i = 0; i < 4; ++i)
                #pragma unroll
                for (int j = 0; j < 4; ++j)
                    acc[i][j] = __builtin_amdgcn_mfma_f32_16x16x32_bf16(ah[i], bl[j], acc[i][j], 0, 0, 0);
            #pragma unroll
            for (int i = 0; i < 4; ++i)
                #pragma unroll
                for (int j = 0; j < 4; ++j)
                    acc[i][j] = __builtin_amdgcn_mfma_f32_16x16x32_bf16(al[i], bh[j], acc[i][j], 0, 0, 0);
        }
    }
    #pragma unroll
    for (int i = 0; i < 4; ++i) {
        int mrow = m0 + wm + i * 16 + (lane >> 4) * 4;
        #pragma unroll
        for (int j = 0; j < 4; ++j) {
            int col = n0 + wn + j * 16 + fr;
            #pragma unroll
            for (int r = 0; r < 4; ++r)
                C[(size_t)(mrow + r) * DIM + col] = acc[i][j][r];
        }
    }
    // ---- fused attvec partials over this block's 128-col slice ----
    float av[4], dv[4];
    #pragma unroll
    for (int j = 0; j < 4; ++j) {
        int col = n0 + wn + j * 16 + fr;
        av[j] = asrc[col];
        dv[j] = adst[col];
    }
    if (t < 128) { asl[t] = 0.f; adl[t] = 0.f; }
    __syncthreads();
    #pragma unroll
    for (int ph = 0; ph < 2; ++ph) {      // ph 0: wn==0 warps write; ph 1: wn==64 warps add
        if ((wn == 0) == (ph == 0)) {
            #pragma unroll
            for (int i = 0; i < 4; ++i)
                #pragma unroll
                for (int r = 0; r < 4; ++r) {
                    float sa = acc[i][0][r] * av[0] + acc[i][1][r] * av[1]
                             + acc[i][2][r] * av[2] + acc[i][3][r] * av[3];
                    float sd = acc[i][0][r] * dv[0] + acc[i][1][r] * dv[1]
                             + acc[i][2][r] * dv[2] + acc[i][3][r] * dv[3];
                    #pragma unroll
                    for (int off = 1; off < 16; off <<= 1) {
                        sa += __shfl_xor(sa, off, 64);
                        sd += __shfl_xor(sd, off, 64);
                    }
                    if (fr == 0) {
                        int rloc = wm + i * 16 + (lane >> 4) * 4 + r;
                        if (ph == 0) { asl[rloc] = sa;  adl[rloc] = sd; }
                        else         { asl[rloc] += sa; adl[rloc] += sd; }
                    }
                }
        }
        __syncthreads();
    }
    if (t < 128) {
        pas[(size_t)(m0 + t) * 4 + nb] = asl[t];
        pad[(size_t)(m0 + t) * 4 + nb] = adl[t];
    }
}

// ---------------- finish attvec: sum 4 n-block partials (fixed order) ----------------
__global__ void attvec_fin(const float* __restrict__ pas, const float* __restrict__ pad,
                           float* __restrict__ as_, float* __restrict__ ad_) {
    int id = blockIdx.x * 256 + threadIdx.x;    // row over B*N
    float4 a = *(const float4*)(pas + (size_t)id * 4);
    float4 d = *(const float4*)(pad + (size_t)id * 4);
    as_[id] = ((a.x + a.y) + a.z) + a.w;
    ad_[id] = ((d.x + d.y) + d.z) + d.w;
}

// ---------------- GAT attention + aggregation: wave-per-node, float4 gathers ----------------
// PROVEN form (40.3 us, VGPR 36, occ 52%). Three restructure attempts (R12 batching,
// R13 reg-cache, R16 inline-asm pinning) were neutral or worse -- do not touch.
template<int RELU, int SPLIT>
__global__ __launch_bounds__(256) void aggr_kernel(const float* __restrict__ hp, const int* __restrict__ nbr,
                                                   const float* __restrict__ as_, const float* __restrict__ ad_,
                                                   const float* __restrict__ bias,
                                                   float* __restrict__ outf,
                                                   unsigned short* __restrict__ oh,
                                                   unsigned short* __restrict__ ol) {
    __shared__ float attL[4][KP1];
    __shared__ int   jjL[4][KP1];
    int bid = blockIdx.x;                 // B*N/4 blocks
    int b = bid & (BATCH - 1);
    int w = threadIdx.x >> 6, l = threadIdx.x & 63;
    int n = (bid >> 4) * 4 + w;
    int id = b * NNODE + n;

    float e = -INFINITY;
    if (l < KP1) {
        int j = nbr[id * KP1 + l];
        jjL[w][l] = j;
        e = as_[b * NNODE + j] + ad_[id];
        e = (e >= 0.f) ? e : NEG * e;
    }
    float mx = e;
    #pragma unroll
    for (int off = 16; off > 0; off >>= 1) mx = fmaxf(mx, __shfl_xor(mx, off, 64));
    float ex = (l < KP1) ? expf(e - mx) : 0.f;
    float sm = ex;
    #pragma unroll
    for (int off = 16; off > 0; off >>= 1) sm += __shfl_xor(sm, off, 64);
    if (l < KP1) attL[w][l] = ex / sm;

    const float* base = hp + (size_t)b * NNODE * DIM;
    int d0 = l * 8;
    const float4* b4 = (const float4*)(bias + d0);
    float4 o0 = b4[0], o1 = b4[1];
    #pragma unroll
    for (int k = 0; k < KP1; ++k) {
        float a = attL[w][k];
        const float* vp = base + (size_t)jjL[w][k] * DIM + d0;
        float4 v0 = *(const float4*)vp;
        float4 v1 = *(const float4*)(vp + 4);
        o0.x += a * v0.x; o0.y += a * v0.y; o0.z += a * v0.z; o0.w += a * v0.w;
        o1.x += a * v1.x; o1.y += a * v1.y; o1.z += a * v1.z; o1.w += a * v1.w;
    }
    if (RELU) {
        o0.x = fmaxf(o0.x, 0.f); o0.y = fmaxf(o0.y, 0.f); o0.z = fmaxf(o0.z, 0.f); o0.w = fmaxf(o0.w, 0.f);
        o1.x = fmaxf(o1.x, 0.f); o1.y = fmaxf(o1.y, 0.f); o1.z = fmaxf(o1.z, 0.f); o1.w = fmaxf(o1.w, 0.f);
    }
    size_t idx = (size_t)id * DIM + d0;
    if (SPLIT) {
        float v[8] = {o0.x, o0.y, o0.z, o0.w, o1.x, o1.y, o1.z, o1.w};
        unsigned hi[4], lo[4];
        #pragma unroll
        for (int i = 0; i < 4; ++i) {
            unsigned short h0 = f2bf(v[2 * i]),     h1 = f2bf(v[2 * i + 1]);
            unsigned short l0 = f2bf(v[2 * i] - bf2f(h0));
            unsigned short l1 = f2bf(v[2 * i + 1] - bf2f(h1));
            hi[i] = (unsigned)h0 | ((unsigned)h1 << 16);
            lo[i] = (unsigned)l0 | ((unsigned)l1 << 16);
        }
        *(uint4*)(oh + idx) = *(uint4*)hi;
        *(uint4*)(ol + idx) = *(uint4*)lo;
    } else {
        *(float4*)(outf + idx) = o0;
        *(float4*)(outf + idx + 4) = o1;
    }
}

// ---------------- global max pool: single kernel, monotonic-encoded atomicMax ----------------
__global__ __launch_bounds__(256) void maxpool_atomic(const float* __restrict__ h, unsigned* __restrict__ genc) {
    int b = blockIdx.x, dc = blockIdx.y, ch = blockIdx.z;
    int d = dc * 256 + threadIdx.x;
    const float* p = h + ((size_t)b * NNODE + ch * (NNODE / NCH)) * DIM + d;
    float m = -INFINITY;
    #pragma unroll 4
    for (int n = 0; n < NNODE / NCH; ++n) m = fmaxf(m, p[(size_t)n * DIM]);
    unsigned u = __float_as_uint(m);
    unsigned enc = (u & 0x80000000u) ? ~u : (u | 0x80000000u);   // order-preserving f32->u32
    atomicMax(genc + b * DIM + d, enc);
}

// ---------------- final linear g @ Wc + bc (decodes genc) ----------------
__global__ void final_kernel(const unsigned* __restrict__ genc, const float* __restrict__ Wc,
                             const float* __restrict__ bc, float* __restrict__ out) {
    int b = blockIdx.x, t = threadIdx.x;
    float s0 = 0.f, s1 = 0.f;
    for (int d = t; d < DIM; d += 256) {
        unsigned e = genc[b * DIM + d];
        unsigned u = (e & 0x80000000u) ? (e ^ 0x80000000u) : ~e;
        float v = __uint_as_float(u);
        s0 += v * Wc[d * 2 + 0];
        s1 += v * Wc[d * 2 + 1];
    }
    __shared__ float r0[256], r1[256];
    r0[t] = s0; r1[t] = s1; __syncthreads();
    for (int s = 128; s > 0; s >>= 1) {
        if (t < s) { r0[t] += r0[t + s]; r1[t] += r1[t + s]; }
        __syncthreads();
    }
    if (t == 0) { out[b * 2] = r0[0] + bc[0]; out[b * 2 + 1] = r1[0] + bc[1]; }
}

extern "C" void kernel_launch(void* const* d_in, const int* in_sizes, int n_in,
                              void* d_out, int out_size, void* d_ws, size_t ws_size,
                              hipStream_t stream) {
    const float* x     = (const float*)d_in[0];
    const float* W1    = (const float*)d_in[1];
    const float* asrc1 = (const float*)d_in[2];
    const float* adst1 = (const float*)d_in[3];
    const float* b1    = (const float*)d_in[4];
    const float* W2    = (const float*)d_in[5];
    const float* asrc2 = (const float*)d_in[6];
    const float* adst2 = (const float*)d_in[7];
    const float* b2    = (const float*)d_in[8];
    const float* W3    = (const float*)d_in[9];
    const float* asrc3 = (const float*)d_in[10];
    const float* adst3 = (const float*)d_in[11];
    const float* b3    = (const float*)d_in[12];
    const float* Wc    = (const float*)d_in[13];
    const float* bc    = (const float*)d_in[14];
    float* out = (float*)d_out;

    char* ws = (char*)d_ws;
    unsigned*       keys  = (unsigned*)ws;                         // 64MB (graph build only)
    float*          hp    = (float*)ws;                            // 32MB f32
    unsigned short* hA_hi = (unsigned short*)(ws + (32ull << 20)); // 16MB
    unsigned short* hA_lo = (unsigned short*)(ws + (48ull << 20)); // 16MB
    unsigned short* xh    = (unsigned short*)(ws + (64ull << 20)); // 16MB (graph build only)
    unsigned short* hB_hi = (unsigned short*)(ws + (64ull << 20)); // 16MB
    unsigned short* hB_lo = (unsigned short*)(ws + (80ull << 20)); // 16MB
    float*          h3    = (float*)(ws + (64ull << 20));          // 32MB, alias hB
    size_t off = 96ull << 20;
    unsigned short* Wt1h = (unsigned short*)(ws + off); off += (size_t)DIM * DIM * 2;
    unsigned short* Wt1l = (unsigned short*)(ws + off); off += (size_t)DIM * DIM * 2;
    unsigned short* Wt2h = (unsigned short*)(ws + off); off += (size_t)DIM * DIM * 2;
    unsigned short* Wt2l = (unsigned short*)(ws + off); off += (size_t)DIM * DIM * 2;
    unsigned short* Wt3h = (unsigned short*)(ws + off); off += (size_t)DIM * DIM * 2;
    unsigned short* Wt3l = (unsigned short*)(ws + off); off += (size_t)DIM * DIM * 2;
    int*      nbr    = (int*)(ws + off);      off += (size_t)BATCH * NNODE * KP1 * 4;
    int*      cand   = (int*)(ws + off);      off += (size_t)BATCH * NNODE * NCAND * 4;
    float*    sq     = (float*)(ws + off);    off += (size_t)BATCH * NNODE * 4;
    float*    mean   = (float*)(ws + off);    off += (size_t)BATCH * DIM * 4;
    unsigned* maxabs = (unsigned*)(ws + off); off += 256;
    float*    as_    = (float*)(ws + off);    off += (size_t)BATCH * NNODE * 4;
    float*    ad_    = (float*)(ws + off);    off += (size_t)BATCH * NNODE * 4;
    unsigned* genc   = (unsigned*)(ws + off); off += (size_t)BATCH * DIM * 4;
    float*    part   = (float*)(ws + off);    off += (size_t)BATCH * NCH * DIM * 4;  // 512KB scratch
    float*    pas    = part;                                   // 256KB (reuse, colmean done)
    float*    pad    = part + (size_t)BATCH * NNODE * 4;       // 256KB
    (void)ws_size; (void)in_sizes; (void)n_in; (void)out_size;

    const dim3 cgrid(BATCH, DIM / 256, NCH);
    // ---- graph construction: approx bf16 MFMA keys + exact f32 re-rank ----
    init_misc<<<32, 256, 0, stream>>>(maxabs, genc);
    colmean_part<<<cgrid, 256, 0, stream>>>(x, part);
    colmean_fin<<<BATCH * DIM / 256, 256, 0, stream>>>(part, mean);
    rowsq_xtobf<<<BATCH * NNODE / 4, 256, 0, stream>>>(x, sq, xh);
    dist_mfma<<<(NNODE / BT) * (BATCH * NNODE / BT), 256, 0, stream>>>(xh, sq, keys);
    knn_kernel<<<BATCH * NNODE / 4, 256, 0, stream>>>(keys, cand);
    rerank_kernel<<<BATCH * NNODE / 4, 256, 0, stream>>>(x, sq, cand, nbr);
    // ---- weights transpose + split (one launch) ----
    wsplit_kernel<<<dim3(16, 16, 3), 256, 0, stream>>>(W1, W2, W3, Wt1h, Wt1l, Wt2h, Wt2l, Wt3h, Wt3l);
    // ---- normalize -> hA (split bf16); keys/xh dead from here ----
    maxabs_kernel<<<dim3(16, BATCH), 256, 0, stream>>>(x, mean, maxabs);
    normalize_kernel<<<BATCH * NNODE * DIM / 256, 256, 0, stream>>>(x, mean, maxabs, hA_hi, hA_lo);

    const int ggrid = (DIM / BT) * (BATCH * NNODE / BT);   // 512 blocks (flat, XCD-swizzled)
    // layer 1
    gemm_mfma<<<ggrid, 256, 0, stream>>>(hA_hi, hA_lo, Wt1h, Wt1l, asrc1, adst1, hp, pas, pad);
    attvec_fin<<<BATCH * NNODE / 256, 256, 0, stream>>>(pas, pad, as_, ad_);
    aggr_kernel<1, 1><<<BATCH * NNODE / 4, 256, 0, stream>>>(hp, nbr, as_, ad_, b1, nullptr, hB_hi, hB_lo);
    // layer 2
    gemm_mfma<<<ggrid, 256, 0, stream>>>(hB_hi, hB_lo, Wt2h, Wt2l, asrc2, adst2, hp, pas, pad);
    attvec_fin<<<BATCH * NNODE / 256, 256, 0, stream>>>(pas, pad, as_, ad_);
    aggr_kernel<1, 1><<<BATCH * NNODE / 4, 256, 0, stream>>>(hp, nbr, as_, ad_, b2, nullptr, hA_hi, hA_lo);
    // layer 3
    gemm_mfma<<<ggrid, 256, 0, stream>>>(hA_hi, hA_lo, Wt3h, Wt3l, asrc3, adst3, hp, pas, pad);
    attvec_fin<<<BATCH * NNODE / 256, 256, 0, stream>>>(pas, pad, as_, ad_);
    aggr_kernel<0, 0><<<BATCH * NNODE / 4, 256, 0, stream>>>(hp, nbr, as_, ad_, b3, h3, nullptr, nullptr);
    // pool + classify
    maxpool_atomic<<<cgrid, 256, 0, stream>>>(h3, genc);
    final_kernel<<<BATCH, 256, 0, stream>>>(genc, Wc, bc, out);
}

// Round 19
// 360.973 us; speedup vs baseline: 1.1135x; 1.0175x over previous
//
#include <hip/hip_runtime.h>
#include <hip/hip_bf16.h>
#include <math.h>

#define BATCH 16
#define NNODE 1024
#define DIM   512
#define KNN   16
#define KP1   17
#define NCAND 18
#define NEG   0.2f
#define BT    128   // block tile
#define NCH   16    // n-chunks for column reductions

typedef __attribute__((ext_vector_type(8))) short bf16x8;
typedef __attribute__((ext_vector_type(4))) float f32x4;

// async global->LDS, 16B per lane; LDS dest = wave-uniform base + lane*16 (m104)
#define GLOAD16(g, l) __builtin_amdgcn_global_load_lds( \
    (const __attribute__((address_space(1))) unsigned int*)(g), \
    (__attribute__((address_space(3))) unsigned int*)(l), 16, 0, 0)

__device__ __forceinline__ unsigned short f2bf(float f) {
    unsigned u = __float_as_uint(f);
    unsigned r = (u + 0x7FFFu + ((u >> 16) & 1u)) >> 16;   // RNE
    return (unsigned short)r;
}
__device__ __forceinline__ float bf2f(unsigned short h) {
    return __uint_as_float(((unsigned)h) << 16);
}
__device__ __forceinline__ void split_store(float v, unsigned short* hi, unsigned short* lo, size_t idx) {
    unsigned short h = f2bf(v);
    hi[idx] = h;
    lo[idx] = f2bf(v - bf2f(h));
}

// ---------------- zero maxabs + encoded max-pool accumulator ----------------
__global__ void init_misc(unsigned* __restrict__ maxabs, unsigned* __restrict__ genc) {
    int gid = blockIdx.x * 256 + threadIdx.x;
    if (gid < BATCH) maxabs[gid] = 0u;
    if (gid < BATCH * DIM) genc[gid] = 0u;        // enc(-INF) > 0, so 0 is identity
}

// ---------------- fused pass 1 over x: col-sum partials + row norms + x->bf16 ----------------
// Block (b, ch): 4 waves x 16 rows each. Col-sums accumulate per-lane over the wave's 16
// rows (ascending), written as 64 partials/graph; fin sums (ch,w) lexicographic ==
// ascending rows -> mean bit-identical to the old two-kernel path.
__global__ __launch_bounds__(256) void pass1_kernel(const float* __restrict__ x,
                                                    float* __restrict__ part64,
                                                    float* __restrict__ sq,
                                                    unsigned short* __restrict__ xh) {
    int b = blockIdx.x, ch = blockIdx.y;
    int w = threadIdx.x >> 6, l = threadIdx.x & 63;
    int r0 = ch * 64 + w * 16;
    float cs[8] = {0.f, 0.f, 0.f, 0.f, 0.f, 0.f, 0.f, 0.f};
    for (int rr = 0; rr < 16; ++rr) {
        int row = b * NNODE + r0 + rr;
        const float* p = x + (size_t)row * DIM + l * 8;
        float4 a = *(const float4*)p;
        float4 q = *(const float4*)(p + 4);
        cs[0] += a.x; cs[1] += a.y; cs[2] += a.z; cs[3] += a.w;
        cs[4] += q.x; cs[5] += q.y; cs[6] += q.z; cs[7] += q.w;
        float s = a.x * a.x + a.y * a.y + a.z * a.z + a.w * a.w
                + q.x * q.x + q.y * q.y + q.z * q.z + q.w * q.w;
        ushort4 ha, hb;
        ha.x = f2bf(a.x); ha.y = f2bf(a.y); ha.z = f2bf(a.z); ha.w = f2bf(a.w);
        hb.x = f2bf(q.x); hb.y = f2bf(q.y); hb.z = f2bf(q.z); hb.w = f2bf(q.w);
        unsigned short* qo = xh + (size_t)row * DIM + l * 8;
        *(ushort4*)qo = ha;
        *(ushort4*)(qo + 4) = hb;
        #pragma unroll
        for (int off = 32; off > 0; off >>= 1) s += __shfl_down(s, off, 64);
        if (l == 0) sq[row] = s;
    }
    float* dst = part64 + ((size_t)(b * 64 + ch * 4 + w)) * DIM + l * 8;
    #pragma unroll
    for (int i = 0; i < 8; ++i) dst[i] = cs[i];
}

__global__ void colmean_fin(const float* __restrict__ part64, float* __restrict__ mean) {
    int id = blockIdx.x * 256 + threadIdx.x;   // b*DIM + d
    int b = id >> 9, d = id & (DIM - 1);
    float s = 0.f;
    for (int p = 0; p < 64; ++p) s += part64[((size_t)(b * 64 + p)) * DIM + d];
    mean[id] = s * (1.0f / NNODE);
}

// ---------------- approx distances via bf16 MFMA -> u32 selection keys ----------------
__global__ __launch_bounds__(256, 2) void dist_mfma(const unsigned short* __restrict__ xh,
                                                    const float* __restrict__ sq,
                                                    unsigned* __restrict__ keys) {
    __shared__ unsigned short AhL[128][64], BhL[128][64];
    int fh = blockIdx.x;
    int xcd = fh & 7, ord = fh >> 3;          // ord 0..127
    int mt = xcd * 16 + (ord >> 3);           // 0..127
    int nb = ord & 7;
    int b = mt >> 3;
    int m0 = mt * BT;
    int n0 = nb * BT;
    int bn0 = b * NNODE + n0;
    int t = threadIdx.x;
    int lane = t & 63, w = t >> 6;
    int wm = (w >> 1) * 64, wn = (w & 1) * 64;
    int fr = lane & 15, fk = (lane >> 4) * 8;
    f32x4 acc[4][4];
    #pragma unroll
    for (int i = 0; i < 4; ++i)
        #pragma unroll
        for (int j = 0; j < 4; ++j) acc[i][j] = (f32x4){0.f, 0.f, 0.f, 0.f};

    for (int k0 = 0; k0 < DIM; k0 += 64) {
        if (k0) __syncthreads();
        #pragma unroll
        for (int p = 0; p < 4; ++p) {
            int u = t + p * 256;              // 1024 issues of 16B cover 128x64 bf16
            int row = u >> 3, slot = u & 7;
            int gseg = (slot ^ (row & 7)) * 8;
            GLOAD16(xh + (size_t)(m0 + row) * DIM + k0 + gseg, &AhL[0][0] + u * 8);
            GLOAD16(xh + (size_t)(bn0 + row) * DIM + k0 + gseg, &BhL[0][0] + u * 8);
        }
        __syncthreads();
        #pragma unroll
        for (int s = 0; s < 2; ++s) {
            bf16x8 ah[4], bh[4];
            int ks = s * 4 + (fk >> 3);
            #pragma unroll
            for (int i = 0; i < 4; ++i) {
                int ra = wm + i * 16 + fr;
                ah[i] = *(const bf16x8*)&AhL[ra][(ks ^ (ra & 7)) * 8];
                int rb = wn + i * 16 + fr;
                bh[i] = *(const bf16x8*)&BhL[rb][(ks ^ (rb & 7)) * 8];
            }
            #pragma unroll
            for (int i = 0; i < 4; ++i)
                #pragma unroll
                for (int j = 0; j < 4; ++j)
                    acc[i][j] = __builtin_amdgcn_mfma_f32_16x16x32_bf16(ah[i], bh[j], acc[i][j], 0, 0, 0);
        }
    }
    const float* sqb = sq + b * NNODE;
    int mloc0 = m0 - b * NNODE;
    #pragma unroll
    for (int i = 0; i < 4; ++i) {
        int mloc = mloc0 + wm + i * 16 + (lane >> 4) * 4;
        #pragma unroll
        for (int j = 0; j < 4; ++j) {
            int n = n0 + wn + j * 16 + fr;
            float sqn = sqb[n];
            #pragma unroll
            for (int r = 0; r < 4; ++r) {
                float val = sqb[mloc + r] + sqn - 2.f * acc[i][j][r];
                unsigned kv = (__float_as_uint(val) & 0xFFFFFC00u) | (unsigned)n;
                if (mloc + r == n) kv = 0xFFFFFFFFu;
                keys[((size_t)b * NNODE + mloc + r) * NNODE + n] = kv;
            }
        }
    }
}

// ---------------- top-18 smallest keys per row: threshold walk ----------------
__global__ __launch_bounds__(256) void knn_kernel(const unsigned* __restrict__ keys, int* __restrict__ cand) {
    int row = blockIdx.x * 4 + (threadIdx.x >> 6);   // b*N + n
    int l = threadIdx.x & 63;
    const unsigned* src = keys + (size_t)row * NNODE;
    unsigned key[16];
    #pragma unroll
    for (int j = 0; j < 16; ++j) key[j] = src[l + (j << 6)];
    int* dst = cand + row * NCAND;
    unsigned T = 0;
    for (int it = 0; it < NCAND; ++it) {
        unsigned lmin = 0xFFFFFFFFu;
        #pragma unroll
        for (int j = 0; j < 16; ++j) {
            unsigned k = (key[j] > T) ? key[j] : 0xFFFFFFFFu;
            lmin = min(lmin, k);
        }
        #pragma unroll
        for (int off = 1; off < 64; off <<= 1) {
            unsigned o = (unsigned)__shfl_xor((int)lmin, off, 64);
            lmin = min(lmin, o);
        }
        T = lmin;
        if (l == 0) dst[it] = (int)(lmin & 1023u);
    }
}

// ---------------- exact f32 re-rank: wave per row ----------------
__global__ __launch_bounds__(256) void rerank_kernel(const float* __restrict__ x,
                                                     const float* __restrict__ sq,
                                                     const int* __restrict__ cand,
                                                     int* __restrict__ nbr) {
    int bid = blockIdx.x;                 // 4096 blocks
    int b = bid & (BATCH - 1);
    int w = threadIdx.x >> 6, l = threadIdx.x & 63;
    int m = (bid >> 4) * 4 + w;
    int row = b * NNODE + m;
    const float* xb = x + (size_t)b * NNODE * DIM;
    const float* sqb = sq + b * NNODE;
    const float* xm = xb + (size_t)m * DIM;
    float4 m0v = *(const float4*)(xm + l * 8);
    float4 m1v = *(const float4*)(xm + l * 8 + 4);
    float sqm = sqb[m];

    int idx[NCAND];
    #pragma unroll
    for (int c = 0; c < NCAND; ++c) idx[c] = cand[row * NCAND + c];

    float s[NCAND];
    #pragma unroll
    for (int half = 0; half < 2; ++half) {
        float4 j0[9], j1[9];
        #pragma unroll
        for (int i = 0; i < 9; ++i) {
            const float* xj = xb + (size_t)idx[half * 9 + i] * DIM;
            j0[i] = *(const float4*)(xj + l * 8);
            j1[i] = *(const float4*)(xj + l * 8 + 4);
        }
        #pragma unroll
        for (int i = 0; i < 9; ++i)
            s[half * 9 + i] = m0v.x * j0[i].x + m0v.y * j0[i].y + m0v.z * j0[i].z + m0v.w * j0[i].w
                            + m1v.x * j1[i].x + m1v.y * j1[i].y + m1v.z * j1[i].z + m1v.w * j1[i].w;
    }
    #pragma unroll
    for (int off = 32; off > 0; off >>= 1)
        #pragma unroll
        for (int c = 0; c < NCAND; ++c) s[c] += __shfl_xor(s[c], off, 64);

    unsigned long long key[NCAND];
    #pragma unroll
    for (int c = 0; c < NCAND; ++c) {
        float dv = sqm + sqb[idx[c]] - 2.f * s[c];
        key[c] = ((unsigned long long)__float_as_uint(dv) << 32) | (unsigned)idx[c];
    }
    unsigned long long mykey = ~0ull;
    int myidx = 0;
    #pragma unroll
    for (int c = 0; c < NCAND; ++c) {
        if (l == c) { mykey = key[c]; myidx = idx[c]; }
    }
    int rank = 0;
    #pragma unroll
    for (int c = 0; c < NCAND; ++c) rank += (key[c] < mykey) ? 1 : 0;

    int* dst = nbr + row * KP1;
    if (l < NCAND && rank < KNN) dst[rank] = myidx;
    if (l == 0) dst[KNN] = m;
}

// ---------------- per-graph max|x - mean| ----------------
__global__ __launch_bounds__(256) void maxabs_kernel(const float* __restrict__ x,
                                                     const float* __restrict__ mean,
                                                     unsigned* __restrict__ maxabs) {
    int b = blockIdx.y;
    const float* p = x + ((size_t)b * NNODE + blockIdx.x * 64) * DIM;
    const float* mb = mean + b * DIM;
    float m = 0.f;
    for (int i = threadIdx.x; i < 64 * DIM; i += 256) {
        int d = i & (DIM - 1);
        m = fmaxf(m, fabsf(p[i] - mb[d]));
    }
    __shared__ float red[256];
    red[threadIdx.x] = m; __syncthreads();
    for (int s = 128; s > 0; s >>= 1) {
        if (threadIdx.x < s) red[threadIdx.x] = fmaxf(red[threadIdx.x], red[threadIdx.x + s]);
        __syncthreads();
    }
    if (threadIdx.x == 0) atomicMax(maxabs + b, __float_as_uint(red[0]));
}

// ---------------- h0 = (x - mean) * 0.999999/maxabs -> split bf16 hi/lo ----------------
__global__ void normalize_kernel(const float* __restrict__ x, const float* __restrict__ mean,
                                 const unsigned* __restrict__ maxabs,
                                 unsigned short* __restrict__ h_hi, unsigned short* __restrict__ h_lo) {
    int id = blockIdx.x * 256 + threadIdx.x;
    int b = id >> 19;
    int d = id & (DIM - 1);
    float scale = 0.999999f / __uint_as_float(maxabs[b]);
    float v = (x[id] - mean[b * DIM + d]) * scale;
    split_store(v, h_hi, h_lo, id);
}

// ---------------- W[512x512] -> Wt hi/lo bf16 [n][k], all 3 layers in one launch ----------------
__global__ void wsplit_kernel(const float* __restrict__ W1, const float* __restrict__ W2,
                              const float* __restrict__ W3,
                              unsigned short* __restrict__ Wh1, unsigned short* __restrict__ Wl1,
                              unsigned short* __restrict__ Wh2, unsigned short* __restrict__ Wl2,
                              unsigned short* __restrict__ Wh3, unsigned short* __restrict__ Wl3) {
    int z = blockIdx.z;
    const float* W = (z == 0) ? W1 : (z == 1) ? W2 : W3;
    unsigned short* Wh = (z == 0) ? Wh1 : (z == 1) ? Wh2 : Wh3;
    unsigned short* Wl = (z == 0) ? Wl1 : (z == 1) ? Wl2 : Wl3;
    __shared__ float tile[32][33];
    int bx = blockIdx.x * 32, by = blockIdx.y * 32;
    int tx = threadIdx.x & 31, ty = threadIdx.x >> 5;
    #pragma unroll
    for (int i = 0; i < 4; ++i)
        tile[ty + i * 8][tx] = W[(size_t)(by + ty + i * 8) * DIM + bx + tx];
    __syncthreads();
    #pragma unroll
    for (int i = 0; i < 4; ++i) {
        int n = bx + ty + i * 8;
        float v = tile[tx][ty + i * 8];
        split_store(v, Wh, Wl, (size_t)n * DIM + by + tx);
    }
}

// ---------------- C f32 = (Ah+Al) . (Wh+Wl) + fused attvec partials ----------------
__global__ __launch_bounds__(256, 2) void gemm_mfma(const unsigned short* __restrict__ Agh,
                                                    const unsigned short* __restrict__ Agl,
                                                    const unsigned short* __restrict__ Bgh,
                                                    const unsigned short* __restrict__ Bgl,
                                                    const float* __restrict__ asrc,
                                                    const float* __restrict__ adst,
                                                    float* __restrict__ C,
                                                    float* __restrict__ pas,
                                                    float* __restrict__ pad) {
    __shared__ unsigned short AhL[128][64], AlL[128][64], BhL[128][64], BlL[128][64];
    __shared__ float asl[128], adl[128];
    int fh = blockIdx.x;
    int xcd = fh & 7, ord = fh >> 3;          // ord 0..63
    int mt = xcd * 16 + (ord >> 2);           // 0..127
    int nb = ord & 3;
    int m0 = mt * BT, n0 = nb * BT;
    int t = threadIdx.x;
    int lane = t & 63, w = t >> 6;
    int wm = (w >> 1) * 64, wn = (w & 1) * 64;
    int fr = lane & 15, fk = (lane >> 4) * 8;
    f32x4 acc[4][4];
    #pragma unroll
    for (int i = 0; i < 4; ++i)
        #pragma unroll
        for (int j = 0; j < 4; ++j) acc[i][j] = (f32x4){0.f, 0.f, 0.f, 0.f};

    for (int k0 = 0; k0 < DIM; k0 += 64) {
        if (k0) __syncthreads();
        #pragma unroll
        for (int p = 0; p < 4; ++p) {
            int u = t + p * 256;
            int row = u >> 3, slot = u & 7;
            int gseg = (slot ^ (row & 7)) * 8;
            size_t ga = (size_t)(m0 + row) * DIM + k0 + gseg;
            size_t gb = (size_t)(n0 + row) * DIM + k0 + gseg;
            GLOAD16(Agh + ga, &AhL[0][0] + u * 8);
            GLOAD16(Agl + ga, &AlL[0][0] + u * 8);
            GLOAD16(Bgh + gb, &BhL[0][0] + u * 8);
            GLOAD16(Bgl + gb, &BlL[0][0] + u * 8);
        }
        __syncthreads();
        #pragma unroll
        for (int s = 0; s < 2; ++s) {
            bf16x8 ah[4], al[4], bh[4], bl[4];
            int ks = s * 4 + (fk >> 3);
            #pragma unroll
            for (int i = 0; i < 4; ++i) {
                int ra = wm + i * 16 + fr;
                int sa = (ks ^ (ra & 7)) * 8;
                ah[i] = *(const bf16x8*)&AhL[ra][sa];
                al[i] = *(const bf16x8*)&AlL[ra][sa];
                int rb = wn + i * 16 + fr;
                int sb = (ks ^ (rb & 7)) * 8;
                bh[i] = *(const bf16x8*)&BhL[rb][sb];
                bl[i] = *(const bf16x8*)&BlL[rb][sb];
            }
            #pragma unroll
            for (int i = 0; i < 4; ++i)
                #pragma unroll
                for (int j = 0; j < 4; ++j)
                    acc[i][j] = __builtin_amdgcn_mfma_f32_16x16x32_bf16(ah[i], bh[j], acc[i][j], 0, 0, 0);
            #pragma unroll
            for (int i = 0; i < 4; ++i)
                #pragma unroll
                for (int j = 0; j < 4; ++j)
                    acc[i][j] = __builtin_amdgcn_mfma_f32_16x16x32_bf16(ah[i], bl[j], acc[i][j], 0, 0, 0);
            #pragma unroll
            for (int i = 0; i < 4; ++i)
                #pragma unroll
                for (int j = 0; j < 4; ++j)
                    acc[i][j] = __builtin_amdgcn_mfma_f32_16x16x32_bf16(al[i], bh[j], acc[i][j], 0, 0, 0);
        }
    }
    #pragma unroll
    for (int i = 0; i < 4; ++i) {
        int mrow = m0 + wm + i * 16 + (lane >> 4) * 4;
        #pragma unroll
        for (int j = 0; j < 4; ++j) {
            int col = n0 + wn + j * 16 + fr;
            #pragma unroll
            for (int r = 0; r < 4; ++r)
                C[(size_t)(mrow + r) * DIM + col] = acc[i][j][r];
        }
    }
    // ---- fused attvec partials over this block's 128-col slice ----
    float av[4], dv[4];
    #pragma unroll
    for (int j = 0; j < 4; ++j) {
        int col = n0 + wn + j * 16 + fr;
        av[j] = asrc[col];
        dv[j] = adst[col];
    }
    if (t < 128) { asl[t] = 0.f; adl[t] = 0.f; }
    __syncthreads();
    #pragma unroll
    for (int ph = 0; ph < 2; ++ph) {      // ph 0: wn==0 warps write; ph 1: wn==64 warps add
        if ((wn == 0) == (ph == 0)) {
            #pragma unroll
            for (int i = 0; i < 4; ++i)
                #pragma unroll
                for (int r = 0; r < 4; ++r) {
                    float sa = acc[i][0][r] * av[0] + acc[i][1][r] * av[1]
                             + acc[i][2][r] * av[2] + acc[i][3][r] * av[3];
                    float sd = acc[i][0][r] * dv[0] + acc[i][1][r] * dv[1]
                             + acc[i][2][r] * dv[2] + acc[i][3][r] * dv[3];
                    #pragma unroll
                    for (int off = 1; off < 16; off <<= 1) {
                        sa += __shfl_xor(sa, off, 64);
                        sd += __shfl_xor(sd, off, 64);
                    }
                    if (fr == 0) {
                        int rloc = wm + i * 16 + (lane >> 4) * 4 + r;
                        if (ph == 0) { asl[rloc] = sa;  adl[rloc] = sd; }
                        else         { asl[rloc] += sa; adl[rloc] += sd; }
                    }
                }
        }
        __syncthreads();
    }
    if (t < 128) {
        pas[(size_t)(m0 + t) * 4 + nb] = asl[t];
        pad[(size_t)(m0 + t) * 4 + nb] = adl[t];
    }
}

// ---------------- GAT attention + aggregation: wave-per-node, float4 gathers ----------------
// PROVEN gather form (40.3 us). attvec_fin folded in: e-terms reduced from pas/pad inline
// in the exact same ((x+y)+z)+w order -> bit-identical attention.
template<int RELU, int SPLIT>
__global__ __launch_bounds__(256) void aggr_kernel(const float* __restrict__ hp, const int* __restrict__ nbr,
                                                   const float* __restrict__ pas, const float* __restrict__ pad,
                                                   const float* __restrict__ bias,
                                                   float* __restrict__ outf,
                                                   unsigned short* __restrict__ oh,
                                                   unsigned short* __restrict__ ol) {
    __shared__ float attL[4][KP1];
    __shared__ int   jjL[4][KP1];
    int bid = blockIdx.x;                 // B*N/4 blocks
    int b = bid & (BATCH - 1);
    int w = threadIdx.x >> 6, l = threadIdx.x & 63;
    int n = (bid >> 4) * 4 + w;
    int id = b * NNODE + n;

    float e = -INFINITY;
    if (l < KP1) {
        int j = nbr[id * KP1 + l];
        jjL[w][l] = j;
        float4 pa = *(const float4*)(pas + (size_t)(b * NNODE + j) * 4);
        float4 pd = *(const float4*)(pad + (size_t)id * 4);
        float es = ((pa.x + pa.y) + pa.z) + pa.w;
        float ed = ((pd.x + pd.y) + pd.z) + pd.w;
        e = es + ed;
        e = (e >= 0.f) ? e : NEG * e;
    }
    float mx = e;
    #pragma unroll
    for (int off = 16; off > 0; off >>= 1) mx = fmaxf(mx, __shfl_xor(mx, off, 64));
    float ex = (l < KP1) ? expf(e - mx) : 0.f;
    float sm = ex;
    #pragma unroll
    for (int off = 16; off > 0; off >>= 1) sm += __shfl_xor(sm, off, 64);
    if (l < KP1) attL[w][l] = ex / sm;

    const float* base = hp + (size_t)b * NNODE * DIM;
    int d0 = l * 8;
    const float4* b4 = (const float4*)(bias + d0);
    float4 o0 = b4[0], o1 = b4[1];
    #pragma unroll
    for (int k = 0; k < KP1; ++k) {
        float a = attL[w][k];
        const float* vp = base + (size_t)jjL[w][k] * DIM + d0;
        float4 v0 = *(const float4*)vp;
        float4 v1 = *(const float4*)(vp + 4);
        o0.x += a * v0.x; o0.y += a * v0.y; o0.z += a * v0.z; o0.w += a * v0.w;
        o1.x += a * v1.x; o1.y += a * v1.y; o1.z += a * v1.z; o1.w += a * v1.w;
    }
    if (RELU) {
        o0.x = fmaxf(o0.x, 0.f); o0.y = fmaxf(o0.y, 0.f); o0.z = fmaxf(o0.z, 0.f); o0.w = fmaxf(o0.w, 0.f);
        o1.x = fmaxf(o1.x, 0.f); o1.y = fmaxf(o1.y, 0.f); o1.z = fmaxf(o1.z, 0.f); o1.w = fmaxf(o1.w, 0.f);
    }
    size_t idx = (size_t)id * DIM + d0;
    if (SPLIT) {
        float v[8] = {o0.x, o0.y, o0.z, o0.w, o1.x, o1.y, o1.z, o1.w};
        unsigned hi[4], lo[4];
        #pragma unroll
        for (int i = 0; i < 4; ++i) {
            unsigned short h0 = f2bf(v[2 * i]),     h1 = f2bf(v[2 * i + 1]);
            unsigned short l0 = f2bf(v[2 * i] - bf2f(h0));
            unsigned short l1 = f2bf(v[2 * i + 1] - bf2f(h1));
            hi[i] = (unsigned)h0 | ((unsigned)h1 << 16);
            lo[i] = (unsigned)l0 | ((unsigned)l1 << 16);
        }
        *(uint4*)(oh + idx) = *(uint4*)hi;
        *(uint4*)(ol + idx) = *(uint4*)lo;
    } else {
        *(float4*)(outf + idx) = o0;
        *(float4*)(outf + idx + 4) = o1;
    }
}

// ---------------- global max pool: single kernel, monotonic-encoded atomicMax ----------------
__global__ __launch_bounds__(256) void maxpool_atomic(const float* __restrict__ h, unsigned* __restrict__ genc) {
    int b = blockIdx.x, dc = blockIdx.y, ch = blockIdx.z;
    int d = dc * 256 + threadIdx.x;
    const float* p = h + ((size_t)b * NNODE + ch * (NNODE / NCH)) * DIM + d;
    float m = -INFINITY;
    #pragma unroll 4
    for (int n = 0; n < NNODE / NCH; ++n) m = fmaxf(m, p[(size_t)n * DIM]);
    unsigned u = __float_as_uint(m);
    unsigned enc = (u & 0x80000000u) ? ~u : (u | 0x80000000u);   // order-preserving f32->u32
    atomicMax(genc + b * DIM + d, enc);
}

// ---------------- final linear g @ Wc + bc (decodes genc) ----------------
__global__ void final_kernel(const unsigned* __restrict__ genc, const float* __restrict__ Wc,
                             const float* __restrict__ bc, float* __restrict__ out) {
    int b = blockIdx.x, t = threadIdx.x;
    float s0 = 0.f, s1 = 0.f;
    for (int d = t; d < DIM; d += 256) {
        unsigned e = genc[b * DIM + d];
        unsigned u = (e & 0x80000000u) ? (e ^ 0x80000000u) : ~e;
        float v = __uint_as_float(u);
        s0 += v * Wc[d * 2 + 0];
        s1 += v * Wc[d * 2 + 1];
    }
    __shared__ float r0[256], r1[256];
    r0[t] = s0; r1[t] = s1; __syncthreads();
    for (int s = 128; s > 0; s >>= 1) {
        if (t < s) { r0[t] += r0[t + s]; r1[t] += r1[t + s]; }
        __syncthreads();
    }
    if (t == 0) { out[b * 2] = r0[0] + bc[0]; out[b * 2 + 1] = r1[0] + bc[1]; }
}

extern "C" void kernel_launch(void* const* d_in, const int* in_sizes, int n_in,
                              void* d_out, int out_size, void* d_ws, size_t ws_size,
                              hipStream_t stream) {
    const float* x     = (const float*)d_in[0];
    const float* W1    = (const float*)d_in[1];
    const float* asrc1 = (const float*)d_in[2];
    const float* adst1 = (const float*)d_in[3];
    const float* b1    = (const float*)d_in[4];
    const float* W2    = (const float*)d_in[5];
    const float* asrc2 = (const float*)d_in[6];
    const float* adst2 = (const float*)d_in[7];
    const float* b2    = (const float*)d_in[8];
    const float* W3    = (const float*)d_in[9];
    const float* asrc3 = (const float*)d_in[10];
    const float* adst3 = (const float*)d_in[11];
    const float* b3    = (const float*)d_in[12];
    const float* Wc    = (const float*)d_in[13];
    const float* bc    = (const float*)d_in[14];
    float* out = (float*)d_out;

    char* ws = (char*)d_ws;
    unsigned*       keys  = (unsigned*)ws;                         // 64MB (graph build only)
    float*          hp    = (float*)ws;                            // 32MB f32
    unsigned short* hA_hi = (unsigned short*)(ws + (32ull << 20)); // 16MB
    unsigned short* hA_lo = (unsigned short*)(ws + (48ull << 20)); // 16MB
    unsigned short* xh    = (unsigned short*)(ws + (64ull << 20)); // 16MB (graph build only)
    unsigned short* hB_hi = (unsigned short*)(ws + (64ull << 20)); // 16MB
    unsigned short* hB_lo = (unsigned short*)(ws + (80ull << 20)); // 16MB
    float*          h3    = (float*)(ws + (64ull << 20));          // 32MB, alias hB
    size_t off = 96ull << 20;
    unsigned short* Wt1h = (unsigned short*)(ws + off); off += (size_t)DIM * DIM * 2;
    unsigned short* Wt1l = (unsigned short*)(ws + off); off += (size_t)DIM * DIM * 2;
    unsigned short* Wt2h = (unsigned short*)(ws + off); off += (size_t)DIM * DIM * 2;
    unsigned short* Wt2l = (unsigned short*)(ws + off); off += (size_t)DIM * DIM * 2;
    unsigned short* Wt3h = (unsigned short*)(ws + off); off += (size_t)DIM * DIM * 2;
    unsigned short* Wt3l = (unsigned short*)(ws + off); off += (size_t)DIM * DIM * 2;
    int*      nbr    = (int*)(ws + off);      off += (size_t)BATCH * NNODE * KP1 * 4;
    int*      cand   = (int*)(ws + off);      off += (size_t)BATCH * NNODE * NCAND * 4;
    float*    sq     = (float*)(ws + off);    off += (size_t)BATCH * NNODE * 4;
    float*    mean   = (float*)(ws + off);    off += (size_t)BATCH * DIM * 4;
    unsigned* maxabs = (unsigned*)(ws + off); off += 256;
    unsigned* genc   = (unsigned*)(ws + off); off += (size_t)BATCH * DIM * 4;
    float*    part64 = (float*)(ws + off);    off += (size_t)BATCH * 64 * DIM * 4;   // 2MB
    float*    pas    = (float*)(ws + off);    off += (size_t)BATCH * NNODE * 4 * 4;  // 256KB
    float*    pad    = (float*)(ws + off);    off += (size_t)BATCH * NNODE * 4 * 4;  // 256KB
    (void)ws_size; (void)in_sizes; (void)n_in; (void)out_size;

    // ---- graph construction: fused pass1 + approx bf16 MFMA keys + exact f32 re-rank ----
    init_misc<<<32, 256, 0, stream>>>(maxabs, genc);
    pass1_kernel<<<dim3(BATCH, NCH), 256, 0, stream>>>(x, part64, sq, xh);
    colmean_fin<<<BATCH * DIM / 256, 256, 0, stream>>>(part64, mean);
    dist_mfma<<<(NNODE / BT) * (BATCH * NNODE / BT), 256, 0, stream>>>(xh, sq, keys);
    knn_kernel<<<BATCH * NNODE / 4, 256, 0, stream>>>(keys, cand);
    rerank_kernel<<<BATCH * NNODE / 4, 256, 0, stream>>>(x, sq, cand, nbr);
    // ---- weights transpose + split (one launch) ----
    wsplit_kernel<<<dim3(16, 16, 3), 256, 0, stream>>>(W1, W2, W3, Wt1h, Wt1l, Wt2h, Wt2l, Wt3h, Wt3l);
    // ---- normalize -> hA (split bf16); keys/xh dead from here ----
    maxabs_kernel<<<dim3(16, BATCH), 256, 0, stream>>>(x, mean, maxabs);
    normalize_kernel<<<BATCH * NNODE * DIM / 256, 256, 0, stream>>>(x, mean, maxabs, hA_hi, hA_lo);

    const int ggrid = (DIM / BT) * (BATCH * NNODE / BT);   // 512 blocks (flat, XCD-swizzled)
    // layer 1
    gemm_mfma<<<ggrid, 256, 0, stream>>>(hA_hi, hA_lo, Wt1h, Wt1l, asrc1, adst1, hp, pas, pad);
    aggr_kernel<1, 1><<<BATCH * NNODE / 4, 256, 0, stream>>>(hp, nbr, pas, pad, b1, nullptr, hB_hi, hB_lo);
    // layer 2
    gemm_mfma<<<ggrid, 256, 0, stream>>>(hB_hi, hB_lo, Wt2h, Wt2l, asrc2, adst2, hp, pas, pad);
    aggr_kernel<1, 1><<<BATCH * NNODE / 4, 256, 0, stream>>>(hp, nbr, pas, pad, b2, nullptr, hA_hi, hA_lo);
    // layer 3
    gemm_mfma<<<ggrid, 256, 0, stream>>>(hA_hi, hA_lo, Wt3h, Wt3l, asrc3, adst3, hp, pas, pad);
    aggr_kernel<0, 0><<<BATCH * NNODE / 4, 256, 0, stream>>>(hp, nbr, pas, pad, b3, h3, nullptr, nullptr);
    // pool + classify
    maxpool_atomic<<<dim3(BATCH, DIM / 256, NCH), 256, 0, stream>>>(h3, genc);
    final_kernel<<<BATCH, 256, 0, stream>>>(genc, Wc, bc, out);
}

// Round 20
// 350.027 us; speedup vs baseline: 1.1483x; 1.0313x over previous
//
#include <hip/hip_runtime.h>
#include <hip/hip_bf16.h>
#include <math.h>

#define BATCH 16
#define NNODE 1024
#define DIM   512
#define KNN   16
#define KP1   17
#define NCAND 18
#define NEG   0.2f
#define BT    128   // block tile
#define NCH   16    // n-chunks for column reductions

typedef __attribute__((ext_vector_type(8))) short bf16x8;
typedef __attribute__((ext_vector_type(4))) float f32x4;

// async global->LDS, 16B per lane; LDS dest = wave-uniform base + lane*16 (m104)
#define GLOAD16(g, l) __builtin_amdgcn_global_load_lds( \
    (const __attribute__((address_space(1))) unsigned int*)(g), \
    (__attribute__((address_space(3))) unsigned int*)(l), 16, 0, 0)

__device__ __forceinline__ unsigned short f2bf(float f) {
    unsigned u = __float_as_uint(f);
    unsigned r = (u + 0x7FFFu + ((u >> 16) & 1u)) >> 16;   // RNE
    return (unsigned short)r;
}
__device__ __forceinline__ float bf2f(unsigned short h) {
    return __uint_as_float(((unsigned)h) << 16);
}
__device__ __forceinline__ void split_store(float v, unsigned short* hi, unsigned short* lo, size_t idx) {
    unsigned short h = f2bf(v);
    hi[idx] = h;
    lo[idx] = f2bf(v - bf2f(h));
}

// ---------------- zero maxabs + encoded max-pool accumulator ----------------
__global__ void init_misc(unsigned* __restrict__ maxabs, unsigned* __restrict__ genc) {
    int gid = blockIdx.x * 256 + threadIdx.x;
    if (gid < BATCH) maxabs[gid] = 0u;
    if (gid < BATCH * DIM) genc[gid] = 0u;        // enc(-INF) > 0, so 0 is identity
}

// ---------------- fused pass 1 over x: col-sum partials + row norms + x->bf16 ----------------
__global__ __launch_bounds__(256) void pass1_kernel(const float* __restrict__ x,
                                                    float* __restrict__ part64,
                                                    float* __restrict__ sq,
                                                    unsigned short* __restrict__ xh) {
    int b = blockIdx.x, ch = blockIdx.y;
    int w = threadIdx.x >> 6, l = threadIdx.x & 63;
    int r0 = ch * 64 + w * 16;
    float cs[8] = {0.f, 0.f, 0.f, 0.f, 0.f, 0.f, 0.f, 0.f};
    for (int rr = 0; rr < 16; ++rr) {
        int row = b * NNODE + r0 + rr;
        const float* p = x + (size_t)row * DIM + l * 8;
        float4 a = *(const float4*)p;
        float4 q = *(const float4*)(p + 4);
        cs[0] += a.x; cs[1] += a.y; cs[2] += a.z; cs[3] += a.w;
        cs[4] += q.x; cs[5] += q.y; cs[6] += q.z; cs[7] += q.w;
        float s = a.x * a.x + a.y * a.y + a.z * a.z + a.w * a.w
                + q.x * q.x + q.y * q.y + q.z * q.z + q.w * q.w;
        ushort4 ha, hb;
        ha.x = f2bf(a.x); ha.y = f2bf(a.y); ha.z = f2bf(a.z); ha.w = f2bf(a.w);
        hb.x = f2bf(q.x); hb.y = f2bf(q.y); hb.z = f2bf(q.z); hb.w = f2bf(q.w);
        unsigned short* qo = xh + (size_t)row * DIM + l * 8;
        *(ushort4*)qo = ha;
        *(ushort4*)(qo + 4) = hb;
        #pragma unroll
        for (int off = 32; off > 0; off >>= 1) s += __shfl_down(s, off, 64);
        if (l == 0) sq[row] = s;
    }
    float* dst = part64 + ((size_t)(b * 64 + ch * 4 + w)) * DIM + l * 8;
    #pragma unroll
    for (int i = 0; i < 8; ++i) dst[i] = cs[i];
}

__global__ void colmean_fin(const float* __restrict__ part64, float* __restrict__ mean) {
    int id = blockIdx.x * 256 + threadIdx.x;   // b*DIM + d
    int b = id >> 9, d = id & (DIM - 1);
    float s = 0.f;
    for (int p = 0; p < 64; ++p) s += part64[((size_t)(b * 64 + p)) * DIM + d];
    mean[id] = s * (1.0f / NNODE);
}

// ---------------- approx distances via bf16 MFMA -> u32 selection keys ----------------
// LDS is only 33KB (A+B bf16): 4 blocks/CU fit -> launch_bounds(256,4) for latency hiding.
__global__ __launch_bounds__(256, 4) void dist_mfma(const unsigned short* __restrict__ xh,
                                                    const float* __restrict__ sq,
                                                    unsigned* __restrict__ keys) {
    __shared__ unsigned short AhL[128][64], BhL[128][64];
    int fh = blockIdx.x;
    int xcd = fh & 7, ord = fh >> 3;          // ord 0..127
    int mt = xcd * 16 + (ord >> 3);           // 0..127
    int nb = ord & 7;
    int b = mt >> 3;
    int m0 = mt * BT;
    int n0 = nb * BT;
    int bn0 = b * NNODE + n0;
    int t = threadIdx.x;
    int lane = t & 63, w = t >> 6;
    int wm = (w >> 1) * 64, wn = (w & 1) * 64;
    int fr = lane & 15, fk = (lane >> 4) * 8;
    f32x4 acc[4][4];
    #pragma unroll
    for (int i = 0; i < 4; ++i)
        #pragma unroll
        for (int j = 0; j < 4; ++j) acc[i][j] = (f32x4){0.f, 0.f, 0.f, 0.f};

    for (int k0 = 0; k0 < DIM; k0 += 64) {
        if (k0) __syncthreads();
        #pragma unroll
        for (int p = 0; p < 4; ++p) {
            int u = t + p * 256;              // 1024 issues of 16B cover 128x64 bf16
            int row = u >> 3, slot = u & 7;
            int gseg = (slot ^ (row & 7)) * 8;
            GLOAD16(xh + (size_t)(m0 + row) * DIM + k0 + gseg, &AhL[0][0] + u * 8);
            GLOAD16(xh + (size_t)(bn0 + row) * DIM + k0 + gseg, &BhL[0][0] + u * 8);
        }
        __syncthreads();
        #pragma unroll
        for (int s = 0; s < 2; ++s) {
            bf16x8 ah[4], bh[4];
            int ks = s * 4 + (fk >> 3);
            #pragma unroll
            for (int i = 0; i < 4; ++i) {
                int ra = wm + i * 16 + fr;
                ah[i] = *(const bf16x8*)&AhL[ra][(ks ^ (ra & 7)) * 8];
                int rb = wn + i * 16 + fr;
                bh[i] = *(const bf16x8*)&BhL[rb][(ks ^ (rb & 7)) * 8];
            }
            #pragma unroll
            for (int i = 0; i < 4; ++i)
                #pragma unroll
                for (int j = 0; j < 4; ++j)
                    acc[i][j] = __builtin_amdgcn_mfma_f32_16x16x32_bf16(ah[i], bh[j], acc[i][j], 0, 0, 0);
        }
    }
    const float* sqb = sq + b * NNODE;
    int mloc0 = m0 - b * NNODE;
    #pragma unroll
    for (int i = 0; i < 4; ++i) {
        int mloc = mloc0 + wm + i * 16 + (lane >> 4) * 4;
        #pragma unroll
        for (int j = 0; j < 4; ++j) {
            int n = n0 + wn + j * 16 + fr;
            float sqn = sqb[n];
            #pragma unroll
            for (int r = 0; r < 4; ++r) {
                float val = sqb[mloc + r] + sqn - 2.f * acc[i][j][r];
                unsigned kv = (__float_as_uint(val) & 0xFFFFFC00u) | (unsigned)n;
                if (mloc + r == n) kv = 0xFFFFFFFFu;
                keys[((size_t)b * NNODE + mloc + r) * NNODE + n] = kv;
            }
        }
    }
}

// ---------------- top-18 smallest keys per row: threshold walk (wrap-subtract trick) ----------------
// min over {key > T} computed as min(key - (T+1)) + (T+1): keys <= T wrap to huge values.
// Keys are unique and we extract 18 of 1024, so a non-wrapped min always exists ->
// selection is bit-identical to the cmp/select form, at 2/3 the VALU cost.
__global__ __launch_bounds__(256) void knn_kernel(const unsigned* __restrict__ keys, int* __restrict__ cand) {
    int row = blockIdx.x * 4 + (threadIdx.x >> 6);   // b*N + n
    int l = threadIdx.x & 63;
    const unsigned* src = keys + (size_t)row * NNODE;
    unsigned key[16];
    #pragma unroll
    for (int j = 0; j < 16; ++j) key[j] = src[l + (j << 6)];
    int* dst = cand + row * NCAND;
    unsigned Tp1 = 0;                                // T + 1, starts at 0 (T = -1)
    for (int it = 0; it < NCAND; ++it) {
        unsigned lmin = 0xFFFFFFFFu;
        #pragma unroll
        for (int j = 0; j < 16; ++j)
            lmin = min(lmin, key[j] - Tp1);
        #pragma unroll
        for (int off = 1; off < 64; off <<= 1) {
            unsigned o = (unsigned)__shfl_xor((int)lmin, off, 64);
            lmin = min(lmin, o);
        }
        unsigned kmin = lmin + Tp1;
        Tp1 = kmin + 1;
        if (l == 0) dst[it] = (int)(kmin & 1023u);
    }
}

// ---------------- exact f32 re-rank: wave per row ----------------
__global__ __launch_bounds__(256) void rerank_kernel(const float* __restrict__ x,
                                                     const float* __restrict__ sq,
                                                     const int* __restrict__ cand,
                                                     int* __restrict__ nbr) {
    int bid = blockIdx.x;                 // 4096 blocks
    int b = bid & (BATCH - 1);
    int w = threadIdx.x >> 6, l = threadIdx.x & 63;
    int m = (bid >> 4) * 4 + w;
    int row = b * NNODE + m;
    const float* xb = x + (size_t)b * NNODE * DIM;
    const float* sqb = sq + b * NNODE;
    const float* xm = xb + (size_t)m * DIM;
    float4 m0v = *(const float4*)(xm + l * 8);
    float4 m1v = *(const float4*)(xm + l * 8 + 4);
    float sqm = sqb[m];

    int idx[NCAND];
    #pragma unroll
    for (int c = 0; c < NCAND; ++c) idx[c] = cand[row * NCAND + c];

    float s[NCAND];
    #pragma unroll
    for (int half = 0; half < 2; ++half) {
        float4 j0[9], j1[9];
        #pragma unroll
        for (int i = 0; i < 9; ++i) {
            const float* xj = xb + (size_t)idx[half * 9 + i] * DIM;
            j0[i] = *(const float4*)(xj + l * 8);
            j1[i] = *(const float4*)(xj + l * 8 + 4);
        }
        #pragma unroll
        for (int i = 0; i < 9; ++i)
            s[half * 9 + i] = m0v.x * j0[i].x + m0v.y * j0[i].y + m0v.z * j0[i].z + m0v.w * j0[i].w
                            + m1v.x * j1[i].x + m1v.y * j1[i].y + m1v.z * j1[i].z + m1v.w * j1[i].w;
    }
    #pragma unroll
    for (int off = 32; off > 0; off >>= 1)
        #pragma unroll
        for (int c = 0; c < NCAND; ++c) s[c] += __shfl_xor(s[c], off, 64);

    unsigned long long key[NCAND];
    #pragma unroll
    for (int c = 0; c < NCAND; ++c) {
        float dv = sqm + sqb[idx[c]] - 2.f * s[c];
        key[c] = ((unsigned long long)__float_as_uint(dv) << 32) | (unsigned)idx[c];
    }
    unsigned long long mykey = ~0ull;
    int myidx = 0;
    #pragma unroll
    for (int c = 0; c < NCAND; ++c) {
        if (l == c) { mykey = key[c]; myidx = idx[c]; }
    }
    int rank = 0;
    #pragma unroll
    for (int c = 0; c < NCAND; ++c) rank += (key[c] < mykey) ? 1 : 0;

    int* dst = nbr + row * KP1;
    if (l < NCAND && rank < KNN) dst[rank] = myidx;
    if (l == 0) dst[KNN] = m;
}

// ---------------- per-graph max|x - mean| ----------------
__global__ __launch_bounds__(256) void maxabs_kernel(const float* __restrict__ x,
                                                     const float* __restrict__ mean,
                                                     unsigned* __restrict__ maxabs) {
    int b = blockIdx.y;
    const float* p = x + ((size_t)b * NNODE + blockIdx.x * 64) * DIM;
    const float* mb = mean + b * DIM;
    float m = 0.f;
    for (int i = threadIdx.x; i < 64 * DIM; i += 256) {
        int d = i & (DIM - 1);
        m = fmaxf(m, fabsf(p[i] - mb[d]));
    }
    __shared__ float red[256];
    red[threadIdx.x] = m; __syncthreads();
    for (int s = 128; s > 0; s >>= 1) {
        if (threadIdx.x < s) red[threadIdx.x] = fmaxf(red[threadIdx.x], red[threadIdx.x + s]);
        __syncthreads();
    }
    if (threadIdx.x == 0) atomicMax(maxabs + b, __float_as_uint(red[0]));
}

// ---------------- h0 = (x - mean) * 0.999999/maxabs -> split bf16 hi/lo ----------------
__global__ void normalize_kernel(const float* __restrict__ x, const float* __restrict__ mean,
                                 const unsigned* __restrict__ maxabs,
                                 unsigned short* __restrict__ h_hi, unsigned short* __restrict__ h_lo) {
    int id = blockIdx.x * 256 + threadIdx.x;
    int b = id >> 19;
    int d = id & (DIM - 1);
    float scale = 0.999999f / __uint_as_float(maxabs[b]);
    float v = (x[id] - mean[b * DIM + d]) * scale;
    split_store(v, h_hi, h_lo, id);
}

// ---------------- W[512x512] -> Wt hi/lo bf16 [n][k], all 3 layers in one launch ----------------
__global__ void wsplit_kernel(const float* __restrict__ W1, const float* __restrict__ W2,
                              const float* __restrict__ W3,
                              unsigned short* __restrict__ Wh1, unsigned short* __restrict__ Wl1,
                              unsigned short* __restrict__ Wh2, unsigned short* __restrict__ Wl2,
                              unsigned short* __restrict__ Wh3, unsigned short* __restrict__ Wl3) {
    int z = blockIdx.z;
    const float* W = (z == 0) ? W1 : (z == 1) ? W2 : W3;
    unsigned short* Wh = (z == 0) ? Wh1 : (z == 1) ? Wh2 : Wh3;
    unsigned short* Wl = (z == 0) ? Wl1 : (z == 1) ? Wl2 : Wl3;
    __shared__ float tile[32][33];
    int bx = blockIdx.x * 32, by = blockIdx.y * 32;
    int tx = threadIdx.x & 31, ty = threadIdx.x >> 5;
    #pragma unroll
    for (int i = 0; i < 4; ++i)
        tile[ty + i * 8][tx] = W[(size_t)(by + ty + i * 8) * DIM + bx + tx];
    __syncthreads();
    #pragma unroll
    for (int i = 0; i < 4; ++i) {
        int n = bx + ty + i * 8;
        float v = tile[tx][ty + i * 8];
        split_store(v, Wh, Wl, (size_t)n * DIM + by + tx);
    }
}

// ---------------- C f32 = (Ah+Al) . (Wh+Wl) + fused attvec partials ----------------
__global__ __launch_bounds__(256, 2) void gemm_mfma(const unsigned short* __restrict__ Agh,
                                                    const unsigned short* __restrict__ Agl,
                                                    const unsigned short* __restrict__ Bgh,
                                                    const unsigned short* __restrict__ Bgl,
                                                    const float* __restrict__ asrc,
                                                    const float* __restrict__ adst,
                                                    float* __restrict__ C,
                                                    float* __restrict__ pas,
                                                    float* __restrict__ pad) {
    __shared__ unsigned short AhL[128][64], AlL[128][64], BhL[128][64], BlL[128][64];
    __shared__ float asl[128], adl[128];
    int fh = blockIdx.x;
    int xcd = fh & 7, ord = fh >> 3;          // ord 0..63
    int mt = xcd * 16 + (ord >> 2);           // 0..127
    int nb = ord & 3;
    int m0 = mt * BT, n0 = nb * BT;
    int t = threadIdx.x;
    int lane = t & 63, w = t >> 6;
    int wm = (w >> 1) * 64, wn = (w & 1) * 64;
    int fr = lane & 15, fk = (lane >> 4) * 8;
    f32x4 acc[4][4];
    #pragma unroll
    for (int i = 0; i < 4; ++i)
        #pragma unroll
        for (int j = 0; j < 4; ++j) acc[i][j] = (f32x4){0.f, 0.f, 0.f, 0.f};

    for (int k0 = 0; k0 < DIM; k0 += 64) {
        if (k0) __syncthreads();
        #pragma unroll
        for (int p = 0; p < 4; ++p) {
            int u = t + p * 256;
            int row = u >> 3, slot = u & 7;
            int gseg = (slot ^ (row & 7)) * 8;
            size_t ga = (size_t)(m0 + row) * DIM + k0 + gseg;
            size_t gb = (size_t)(n0 + row) * DIM + k0 + gseg;
            GLOAD16(Agh + ga, &AhL[0][0] + u * 8);
            GLOAD16(Agl + ga, &AlL[0][0] + u * 8);
            GLOAD16(Bgh + gb, &BhL[0][0] + u * 8);
            GLOAD16(Bgl + gb, &BlL[0][0] + u * 8);
        }
        __syncthreads();
        #pragma unroll
        for (int s = 0; s < 2; ++s) {
            bf16x8 ah[4], al[4], bh[4], bl[4];
            int ks = s * 4 + (fk >> 3);
            #pragma unroll
            for (int i = 0; i < 4; ++i) {
                int ra = wm + i * 16 + fr;
                int sa = (ks ^ (ra & 7)) * 8;
                ah[i] = *(const bf16x8*)&AhL[ra][sa];
                al[i] = *(const bf16x8*)&AlL[ra][sa];
                int rb = wn + i * 16 + fr;
                int sb = (ks ^ (rb & 7)) * 8;
                bh[i] = *(const bf16x8*)&BhL[rb][sb];
                bl[i] = *(const bf16x8*)&BlL[rb][sb];
            }
            #pragma unroll
            for (int i = 0; i < 4; ++i)
                #pragma unroll
                for (int j = 0; j < 4; ++j)
                    acc[i][j] = __builtin_amdgcn_mfma_f32_16x16x32_bf16(ah[i], bh[j], acc[i][j], 0, 0, 0);
            #pragma unroll
            for (int i = 0; i < 4; ++i)
                #pragma unroll
                for (int j = 0; j < 4; ++j)
                    acc[i][j] = __builtin_amdgcn_mfma_f32_16x16x32_bf16(ah[i], bl[j], acc[i][j], 0, 0, 0);
            #pragma unroll
            for (int i = 0; i < 4; ++i)
                #pragma unroll
                for (int j = 0; j < 4; ++j)
                    acc[i][j] = __builtin_amdgcn_mfma_f32_16x16x32_bf16(al[i], bh[j], acc[i][j], 0, 0, 0);
        }
    }
    #pragma unroll
    for (int i = 0; i < 4; ++i) {
        int mrow = m0 + wm + i * 16 + (lane >> 4) * 4;
        #pragma unroll
        for (int j = 0; j < 4; ++j) {
            int col = n0 + wn + j * 16 + fr;
            #pragma unroll
            for (int r = 0; r < 4; ++r)
                C[(size_t)(mrow + r) * DIM + col] = acc[i][j][r];
        }
    }
    // ---- fused attvec partials over this block's 128-col slice ----
    float av[4], dv[4];
    #pragma unroll
    for (int j = 0; j < 4; ++j) {
        int col = n0 + wn + j * 16 + fr;
        av[j] = asrc[col];
        dv[j] = adst[col];
    }
    if (t < 128) { asl[t] = 0.f; adl[t] = 0.f; }
    __syncthreads();
    #pragma unroll
    for (int ph = 0; ph < 2; ++ph) {      // ph 0: wn==0 warps write; ph 1: wn==64 warps add
        if ((wn == 0) == (ph == 0)) {
            #pragma unroll
            for (int i = 0; i < 4; ++i)
                #pragma unroll
                for (int r = 0; r < 4; ++r) {
                    float sa = acc[i][0][r] * av[0] + acc[i][1][r] * av[1]
                             + acc[i][2][r] * av[2] + acc[i][3][r] * av[3];
                    float sd = acc[i][0][r] * dv[0] + acc[i][1][r] * dv[1]
                             + acc[i][2][r] * dv[2] + acc[i][3][r] * dv[3];
                    #pragma unroll
                    for (int off = 1; off < 16; off <<= 1) {
                        sa += __shfl_xor(sa, off, 64);
                        sd += __shfl_xor(sd, off, 64);
                    }
                    if (fr == 0) {
                        int rloc = wm + i * 16 + (lane >> 4) * 4 + r;
                        if (ph == 0) { asl[rloc] = sa;  adl[rloc] = sd; }
                        else         { asl[rloc] += sa; adl[rloc] += sd; }
                    }
                }
        }
        __syncthreads();
    }
    if (t < 128) {
        pas[(size_t)(m0 + t) * 4 + nb] = asl[t];
        pad[(size_t)(m0 + t) * 4 + nb] = adl[t];
    }
}

// ---------------- GAT attention + aggregation: wave-per-node, float4 gathers ----------------
// PROVEN gather form (40.3 us). attvec_fin folded in (bit-identical e reduction).
template<int RELU, int SPLIT>
__global__ __launch_bounds__(256) void aggr_kernel(const float* __restrict__ hp, const int* __restrict__ nbr,
                                                   const float* __restrict__ pas, const float* __restrict__ pad,
                                                   const float* __restrict__ bias,
                                                   float* __restrict__ outf,
                                                   unsigned short* __restrict__ oh,
                                                   unsigned short* __restrict__ ol) {
    __shared__ float attL[4][KP1];
    __shared__ int   jjL[4][KP1];
    int bid = blockIdx.x;                 // B*N/4 blocks
    int b = bid & (BATCH - 1);
    int w = threadIdx.x >> 6, l = threadIdx.x & 63;
    int n = (bid >> 4) * 4 + w;
    int id = b * NNODE + n;

    float e = -INFINITY;
    if (l < KP1) {
        int j = nbr[id * KP1 + l];
        jjL[w][l] = j;
        float4 pa = *(const float4*)(pas + (size_t)(b * NNODE + j) * 4);
        float4 pd = *(const float4*)(pad + (size_t)id * 4);
        float es = ((pa.x + pa.y) + pa.z) + pa.w;
        float ed = ((pd.x + pd.y) + pd.z) + pd.w;
        e = es + ed;
        e = (e >= 0.f) ? e : NEG * e;
    }
    float mx = e;
    #pragma unroll
    for (int off = 16; off > 0; off >>= 1) mx = fmaxf(mx, __shfl_xor(mx, off, 64));
    float ex = (l < KP1) ? expf(e - mx) : 0.f;
    float sm = ex;
    #pragma unroll
    for (int off = 16; off > 0; off >>= 1) sm += __shfl_xor(sm, off, 64);
    if (l < KP1) attL[w][l] = ex / sm;

    const float* base = hp + (size_t)b * NNODE * DIM;
    int d0 = l * 8;
    const float4* b4 = (const float4*)(bias + d0);
    float4 o0 = b4[0], o1 = b4[1];
    #pragma unroll
    for (int k = 0; k < KP1; ++k) {
        float a = attL[w][k];
        const float* vp = base + (size_t)jjL[w][k] * DIM + d0;
        float4 v0 = *(const float4*)vp;
        float4 v1 = *(const float4*)(vp + 4);
        o0.x += a * v0.x; o0.y += a * v0.y; o0.z += a * v0.z; o0.w += a * v0.w;
        o1.x += a * v1.x; o1.y += a * v1.y; o1.z += a * v1.z; o1.w += a * v1.w;
    }
    if (RELU) {
        o0.x = fmaxf(o0.x, 0.f); o0.y = fmaxf(o0.y, 0.f); o0.z = fmaxf(o0.z, 0.f); o0.w = fmaxf(o0.w, 0.f);
        o1.x = fmaxf(o1.x, 0.f); o1.y = fmaxf(o1.y, 0.f); o1.z = fmaxf(o1.z, 0.f); o1.w = fmaxf(o1.w, 0.f);
    }
    size_t idx = (size_t)id * DIM + d0;
    if (SPLIT) {
        float v[8] = {o0.x, o0.y, o0.z, o0.w, o1.x, o1.y, o1.z, o1.w};
        unsigned hi[4], lo[4];
        #pragma unroll
        for (int i = 0; i < 4; ++i) {
            unsigned short h0 = f2bf(v[2 * i]),     h1 = f2bf(v[2 * i + 1]);
            unsigned short l0 = f2bf(v[2 * i] - bf2f(h0));
            unsigned short l1 = f2bf(v[2 * i + 1] - bf2f(h1));
            hi[i] = (unsigned)h0 | ((unsigned)h1 << 16);
            lo[i] = (unsigned)l0 | ((unsigned)l1 << 16);
        }
        *(uint4*)(oh + idx) = *(uint4*)hi;
        *(uint4*)(ol + idx) = *(uint4*)lo;
    } else {
        *(float4*)(outf + idx) = o0;
        *(float4*)(outf + idx + 4) = o1;
    }
}

// ---------------- global max pool: single kernel, monotonic-encoded atomicMax ----------------
__global__ __launch_bounds__(256) void maxpool_atomic(const float* __restrict__ h, unsigned* __restrict__ genc) {
    int b = blockIdx.x, dc = blockIdx.y, ch = blockIdx.z;
    int d = dc * 256 + threadIdx.x;
    const float* p = h + ((size_t)b * NNODE + ch * (NNODE / NCH)) * DIM + d;
    float m = -INFINITY;
    #pragma unroll 4
    for (int n = 0; n < NNODE / NCH; ++n) m = fmaxf(m, p[(size_t)n * DIM]);
    unsigned u = __float_as_uint(m);
    unsigned enc = (u & 0x80000000u) ? ~u : (u | 0x80000000u);   // order-preserving f32->u32
    atomicMax(genc + b * DIM + d, enc);
}

// ---------------- final linear g @ Wc + bc (decodes genc) ----------------
__global__ void final_kernel(const unsigned* __restrict__ genc, const float* __restrict__ Wc,
                             const float* __restrict__ bc, float* __restrict__ out) {
    int b = blockIdx.x, t = threadIdx.x;
    float s0 = 0.f, s1 = 0.f;
    for (int d = t; d < DIM; d += 256) {
        unsigned e = genc[b * DIM + d];
        unsigned u = (e & 0x80000000u) ? (e ^ 0x80000000u) : ~e;
        float v = __uint_as_float(u);
        s0 += v * Wc[d * 2 + 0];
        s1 += v * Wc[d * 2 + 1];
    }
    __shared__ float r0[256], r1[256];
    r0[t] = s0; r1[t] = s1; __syncthreads();
    for (int s = 128; s > 0; s >>= 1) {
        if (t < s) { r0[t] += r0[t + s]; r1[t] += r1[t + s]; }
        __syncthreads();
    }
    if (t == 0) { out[b * 2] = r0[0] + bc[0]; out[b * 2 + 1] = r1[0] + bc[1]; }
}

extern "C" void kernel_launch(void* const* d_in, const int* in_sizes, int n_in,
                              void* d_out, int out_size, void* d_ws, size_t ws_size,
                              hipStream_t stream) {
    const float* x     = (const float*)d_in[0];
    const float* W1    = (const float*)d_in[1];
    const float* asrc1 = (const float*)d_in[2];
    const float* adst1 = (const float*)d_in[3];
    const float* b1    = (const float*)d_in[4];
    const float* W2    = (const float*)d_in[5];
    const float* asrc2 = (const float*)d_in[6];
    const float* adst2 = (const float*)d_in[7];
    const float* b2    = (const float*)d_in[8];
    const float* W3    = (const float*)d_in[9];
    const float* asrc3 = (const float*)d_in[10];
    const float* adst3 = (const float*)d_in[11];
    const float* b3    = (const float*)d_in[12];
    const float* Wc    = (const float*)d_in[13];
    const float* bc    = (const float*)d_in[14];
    float* out = (float*)d_out;

    char* ws = (char*)d_ws;
    unsigned*       keys  = (unsigned*)ws;                         // 64MB (graph build only)
    float*          hp    = (float*)ws;                            // 32MB f32
    unsigned short* hA_hi = (unsigned short*)(ws + (32ull << 20)); // 16MB
    unsigned short* hA_lo = (unsigned short*)(ws + (48ull << 20)); // 16MB
    unsigned short* xh    = (unsigned short*)(ws + (64ull << 20)); // 16MB (graph build only)
    unsigned short* hB_hi = (unsigned short*)(ws + (64ull << 20)); // 16MB
    unsigned short* hB_lo = (unsigned short*)(ws + (80ull << 20)); // 16MB
    float*          h3    = (float*)(ws + (64ull << 20));          // 32MB, alias hB
    size_t off = 96ull << 20;
    unsigned short* Wt1h = (unsigned short*)(ws + off); off += (size_t)DIM * DIM * 2;
    unsigned short* Wt1l = (unsigned short*)(ws + off); off += (size_t)DIM * DIM * 2;
    unsigned short* Wt2h = (unsigned short*)(ws + off); off += (size_t)DIM * DIM * 2;
    unsigned short* Wt2l = (unsigned short*)(ws + off); off += (size_t)DIM * DIM * 2;
    unsigned short* Wt3h = (unsigned short*)(ws + off); off += (size_t)DIM * DIM * 2;
    unsigned short* Wt3l = (unsigned short*)(ws + off); off += (size_t)DIM * DIM * 2;
    int*      nbr    = (int*)(ws + off);      off += (size_t)BATCH * NNODE * KP1 * 4;
    int*      cand   = (int*)(ws + off);      off += (size_t)BATCH * NNODE * NCAND * 4;
    float*    sq     = (float*)(ws + off);    off += (size_t)BATCH * NNODE * 4;
    float*    mean   = (float*)(ws + off);    off += (size_t)BATCH * DIM * 4;
    unsigned* maxabs = (unsigned*)(ws + off); off += 256;
    unsigned* genc   = (unsigned*)(ws + off); off += (size_t)BATCH * DIM * 4;
    float*    part64 = (float*)(ws + off);    off += (size_t)BATCH * 64 * DIM * 4;   // 2MB
    float*    pas    = (float*)(ws + off);    off += (size_t)BATCH * NNODE * 4 * 4;  // 256KB
    float*    pad    = (float*)(ws + off);    off += (size_t)BATCH * NNODE * 4 * 4;  // 256KB
    (void)ws_size; (void)in_sizes; (void)n_in; (void)out_size;

    // ---- graph construction: fused pass1 + approx bf16 MFMA keys + exact f32 re-rank ----
    init_misc<<<32, 256, 0, stream>>>(maxabs, genc);
    pass1_kernel<<<dim3(BATCH, NCH), 256, 0, stream>>>(x, part64, sq, xh);
    colmean_fin<<<BATCH * DIM / 256, 256, 0, stream>>>(part64, mean);
    dist_mfma<<<(NNODE / BT) * (BATCH * NNODE / BT), 256, 0, stream>>>(xh, sq, keys);
    knn_kernel<<<BATCH * NNODE / 4, 256, 0, stream>>>(keys, cand);
    rerank_kernel<<<BATCH * NNODE / 4, 256, 0, stream>>>(x, sq, cand, nbr);
    // ---- weights transpose + split (one launch) ----
    wsplit_kernel<<<dim3(16, 16, 3), 256, 0, stream>>>(W1, W2, W3, Wt1h, Wt1l, Wt2h, Wt2l, Wt3h, Wt3l);
    // ---- normalize -> hA (split bf16); keys/xh dead from here ----
    maxabs_kernel<<<dim3(16, BATCH), 256, 0, stream>>>(x, mean, maxabs);
    normalize_kernel<<<BATCH * NNODE * DIM / 256, 256, 0, stream>>>(x, mean, maxabs, hA_hi, hA_lo);

    const int ggrid = (DIM / BT) * (BATCH * NNODE / BT);   // 512 blocks (flat, XCD-swizzled)
    // layer 1
    gemm_mfma<<<ggrid, 256, 0, stream>>>(hA_hi, hA_lo, Wt1h, Wt1l, asrc1, adst1, hp, pas, pad);
    aggr_kernel<1, 1><<<BATCH * NNODE / 4, 256, 0, stream>>>(hp, nbr, pas, pad, b1, nullptr, hB_hi, hB_lo);
    // layer 2
    gemm_mfma<<<ggrid, 256, 0, stream>>>(hB_hi, hB_lo, Wt2h, Wt2l, asrc2, adst2, hp, pas, pad);
    aggr_kernel<1, 1><<<BATCH * NNODE / 4, 256, 0, stream>>>(hp, nbr, pas, pad, b2, nullptr, hA_hi, hA_lo);
    // layer 3
    gemm_mfma<<<ggrid, 256, 0, stream>>>(hA_hi, hA_lo, Wt3h, Wt3l, asrc3, adst3, hp, pas, pad);
    aggr_kernel<0, 0><<<BATCH * NNODE / 4, 256, 0, stream>>>(hp, nbr, pas, pad, b3, h3, nullptr, nullptr);
    // pool + classify
    maxpool_atomic<<<dim3(BATCH, DIM / 256, NCH), 256, 0, stream>>>(h3, genc);
    final_kernel<<<BATCH, 256, 0, stream>>>(genc, Wc, bc, out);
}